// Round 13
// baseline (1733.275 us; speedup 1.0000x reference)
//
#include <hip/hip_runtime.h>
#include <cstdint>
#include <cmath>

// ---------------------------------------------------------------------------
// Informer forward. Round 13: route big N=512 GEMMs (FFN-down, out-proj,
// distill-conv at M=8192) through the 128x128 tile (R12 profile: gemm64 is
// LDS-pipe-bound — 5 ds_read_b128 per 4 MFMAs; gemm128 is 8 per 16, balanced;
// K-loop order identical -> bit-identical C). Rule: 128-tile when
// (M/128)*(N/128) >= 256. jax.random via threefry2x32 (H2, verified R1).
// ---------------------------------------------------------------------------

#define HD __host__ __device__

typedef short short8 __attribute__((ext_vector_type(8)));
typedef float float4v __attribute__((ext_vector_type(4)));

__device__ inline short f2bf(float f) {  // RNE
    unsigned u = __float_as_uint(f);
    unsigned r = u + 0x7FFFu + ((u >> 16) & 1u);
    return (short)(r >> 16);
}

HD inline unsigned rotl32(unsigned x, int r) { return (x << r) | (x >> (32 - r)); }
HD inline void tfround(unsigned& x0, unsigned& x1, int r) {
    x0 += x1; x1 = rotl32(x1, r); x1 ^= x0;
}
HD inline void threefry2x32(unsigned k0, unsigned k1, unsigned c0, unsigned c1,
                            unsigned& o0, unsigned& o1) {
    unsigned ks2 = k0 ^ k1 ^ 0x1BD11BDAu;
    unsigned x0 = c0 + k0, x1 = c1 + k1;
    tfround(x0, x1, 13); tfround(x0, x1, 15); tfround(x0, x1, 26); tfround(x0, x1, 6);
    x0 += k1; x1 += ks2 + 1u;
    tfround(x0, x1, 17); tfround(x0, x1, 29); tfround(x0, x1, 16); tfround(x0, x1, 24);
    x0 += ks2; x1 += k0 + 2u;
    tfround(x0, x1, 13); tfround(x0, x1, 15); tfround(x0, x1, 26); tfround(x0, x1, 6);
    x0 += k0; x1 += k1 + 3u;
    tfround(x0, x1, 17); tfround(x0, x1, 29); tfround(x0, x1, 16); tfround(x0, x1, 24);
    x0 += k1; x1 += ks2 + 4u;
    tfround(x0, x1, 13); tfround(x0, x1, 15); tfround(x0, x1, 26); tfround(x0, x1, 6);
    x0 += ks2; x1 += k0 + 5u;
    o0 = x0; o1 = x1;
}

// ---------------------------------------------------------------------------
// Kernels
// ---------------------------------------------------------------------------

// out = in + PE; outb = bf16(out)
__global__ void pe_add_k(const float* __restrict__ in, float* __restrict__ out,
                         short* __restrict__ outb, int total) {
    int t = blockIdx.x * 256 + threadIdx.x;
    if (t >= total) return;
    int d = t % 512;
    int l = (t / 512) % 512;
    float i2 = (float)(d & ~1);
    float div = expf(i2 * (-0.017988946039016f));  // -ln(10000)/512
    float ang = (float)l * div;
    float v = (d & 1) ? cosf(ang) : sinf(ang);
    float r = in[t] + v;
    out[t] = r;
    outb[t] = f2bf(r);
}

// fp32 [K][N] -> bf16 [N][K] via 32x32 LDS tile
__global__ __launch_bounds__(256) void transpose_bf16_k(const float* __restrict__ in,
                                                        short* __restrict__ out, int K, int N) {
    __shared__ float tile[32][33];
    int k0 = blockIdx.y * 32, n0 = blockIdx.x * 32;
    int c = threadIdx.x & 31, r0 = threadIdx.x >> 5;
    for (int rr = r0; rr < 32; rr += 8)
        tile[rr][c] = in[(size_t)(k0 + rr) * N + n0 + c];
    __syncthreads();
    for (int rr = r0; rr < 32; rr += 8)
        out[(size_t)(n0 + rr) * K + k0 + c] = f2bf(tile[c][rr]);
}

// dist_w (O,I,H) -> bf16 W2T[o][h*512+i]
__global__ void w2t_k(const float* __restrict__ dw, short* __restrict__ out, int total) {
    int t = blockIdx.x * 256 + threadIdx.x;
    if (t >= total) return;
    int kk = t % 1536;
    int o = t / 1536;
    int h = kk / 512, i = kk % 512;
    out[t] = f2bf(dw[(size_t)o * 1536 + i * 3 + h]);
}

// concat biases bq|bk|bv -> bqkv[1536]
__global__ void bcat_k(const float* __restrict__ b0, const float* __restrict__ b1,
                       const float* __restrict__ b2, float* __restrict__ out) {
    int t = blockIdx.x * 256 + threadIdx.x;
    if (t >= 1536) return;
    out[t] = (t < 512) ? b0[t] : (t < 1024 ? b1[t - 512] : b2[t - 1024]);
}

__device__ inline void swizzle_bid(int bid, int nbx, int nby, int& bm, int& bn) {
    if ((nby & 7) == 0) {
        int stripe = nby >> 3;
        int x = bid & 7, w = bid >> 3;
        bn = w % nbx;
        bm = x * stripe + w / nbx;
    } else {
        bn = bid % nbx;
        bm = bid / nbx;
    }
}

// bf16 MFMA GEMM, 128x128 tile, BK=32; A bf16 [M][K], Bt bf16 [N][K].
__global__ __launch_bounds__(256) void gemm128_k(
    const short* __restrict__ A, const short* __restrict__ Bt,
    const float* __restrict__ bias, const float* __restrict__ res,
    float* __restrict__ C32, short* __restrict__ C16,
    int M, int N, int K, int relu, int ldC) {
    __shared__ short As[128 * 40];
    __shared__ short Bs[128 * 40];
    int tid = threadIdx.x;
    int wave = tid >> 6, lane = tid & 63;
    int wy = wave >> 1, wx = wave & 1;
    int rl = lane & 15, quad = lane >> 4;
    int bm, bn;
    swizzle_bid(blockIdx.x, N >> 7, M >> 7, bm, bn);
    bm <<= 7; bn <<= 7;

    float4v acc[4][4];
    #pragma unroll
    for (int i = 0; i < 4; i++)
        #pragma unroll
        for (int j = 0; j < 4; j++) acc[i][j] = (float4v){0.f, 0.f, 0.f, 0.f};

    for (int k0 = 0; k0 < K; k0 += 32) {
        #pragma unroll
        for (int it = 0; it < 2; it++) {
            int c = tid + it * 256;
            int row = c >> 2, seg = c & 3;
            *(float4*)&As[row * 40 + seg * 8] =
                *(const float4*)(A + (size_t)(bm + row) * K + k0 + seg * 8);
        }
        #pragma unroll
        for (int it = 0; it < 2; it++) {
            int c = tid + it * 256;
            int row = c >> 2, seg = c & 3;
            *(float4*)&Bs[row * 40 + seg * 8] =
                *(const float4*)(Bt + (size_t)(bn + row) * K + k0 + seg * 8);
        }
        __syncthreads();
        short8 a[4], b[4];
        #pragma unroll
        for (int i = 0; i < 4; i++)
            a[i] = *(const short8*)&As[(wy * 64 + i * 16 + rl) * 40 + quad * 8];
        #pragma unroll
        for (int j = 0; j < 4; j++)
            b[j] = *(const short8*)&Bs[(wx * 64 + j * 16 + rl) * 40 + quad * 8];
        #pragma unroll
        for (int i = 0; i < 4; i++)
            #pragma unroll
            for (int j = 0; j < 4; j++)
                acc[i][j] = __builtin_amdgcn_mfma_f32_16x16x32_bf16(a[i], b[j], acc[i][j], 0, 0, 0);
        __syncthreads();
    }
    #pragma unroll
    for (int i = 0; i < 4; i++) {
        #pragma unroll
        for (int r = 0; r < 4; r++) {
            int gm = bm + wy * 64 + i * 16 + quad * 4 + r;
            #pragma unroll
            for (int j = 0; j < 4; j++) {
                int gn = bn + wx * 64 + j * 16 + rl;
                float v = acc[i][j][r];
                if (bias) v += bias[gn];
                if (relu) v = fmaxf(v, 0.f);
                if (res) v += res[(size_t)gm * ldC + gn];
                if (C32) C32[(size_t)gm * ldC + gn] = v;
                if (C16) C16[(size_t)gm * ldC + gn] = f2bf(v);
            }
        }
    }
}

// 64x64-tile variant. 4 waves, each 16x64.
__global__ __launch_bounds__(256) void gemm64_k(
    const short* __restrict__ A, const short* __restrict__ Bt,
    const float* __restrict__ bias, const float* __restrict__ res,
    float* __restrict__ C32, short* __restrict__ C16,
    int M, int N, int K, int relu, int ldC) {
    __shared__ short As[64 * 40];
    __shared__ short Bs[64 * 40];
    int tid = threadIdx.x;
    int wave = tid >> 6, lane = tid & 63;
    int rl = lane & 15, quad = lane >> 4;
    int bm, bn;
    swizzle_bid(blockIdx.x, N >> 6, M >> 6, bm, bn);
    bm <<= 6; bn <<= 6;

    float4v acc[4];
    #pragma unroll
    for (int j = 0; j < 4; j++) acc[j] = (float4v){0.f, 0.f, 0.f, 0.f};

    int row = tid >> 2, seg = tid & 3;
    for (int k0 = 0; k0 < K; k0 += 32) {
        *(float4*)&As[row * 40 + seg * 8] =
            *(const float4*)(A + (size_t)(bm + row) * K + k0 + seg * 8);
        *(float4*)&Bs[row * 40 + seg * 8] =
            *(const float4*)(Bt + (size_t)(bn + row) * K + k0 + seg * 8);
        __syncthreads();
        short8 a = *(const short8*)&As[(wave * 16 + rl) * 40 + quad * 8];
        short8 b[4];
        #pragma unroll
        for (int j = 0; j < 4; j++)
            b[j] = *(const short8*)&Bs[(j * 16 + rl) * 40 + quad * 8];
        #pragma unroll
        for (int j = 0; j < 4; j++)
            acc[j] = __builtin_amdgcn_mfma_f32_16x16x32_bf16(a, b[j], acc[j], 0, 0, 0);
        __syncthreads();
    }
    #pragma unroll
    for (int r = 0; r < 4; r++) {
        int gm = bm + wave * 16 + quad * 4 + r;
        #pragma unroll
        for (int j = 0; j < 4; j++) {
            int gn = bn + j * 16 + rl;
            float v = acc[j][r];
            if (bias) v += bias[gn];
            if (relu) v = fmaxf(v, 0.f);
            if (res) v += res[(size_t)gm * ldC + gn];
            if (C32) C32[(size_t)gm * ldC + gn] = v;
            if (C16) C16[(size_t)gm * ldC + gn] = f2bf(v);
        }
    }
}

// idx[j] = threefry(rkey, (j, j+size)).second & mask   (H2, verified R1)
__global__ void ridx_k(unsigned k0, unsigned k1, int size, unsigned mask, int* __restrict__ idx) {
    int j = blockIdx.x * 256 + threadIdx.x;
    if (j >= size) return;
    unsigned o0, o1;
    threefry2x32(k0, k1, (unsigned)j, (unsigned)(j + size), o0, o1);
    idx[j] = (int)(o1 & mask);
}

// msamp, K-slab in LDS. One block per (b, h, l-half); grid 16*8*2 = 256.
extern __shared__ float kslab[];
__global__ __launch_bounds__(256) void msamp_lds_k(
    const float* __restrict__ Qp, const float* __restrict__ Kp,
    const int* __restrict__ idx, float* __restrict__ Mout,
    int LQ, int LK, int U, int ld) {
    int bid = blockIdx.x;
    int half = bid & 1;
    int bh = bid >> 1;
    int h = bh & 7, b = bh >> 3;
    const float* kbase = Kp + (size_t)b * LK * ld + h * 64;
    for (int t = threadIdx.x; t < LK * 16; t += 256) {
        int r = t >> 4, seg = t & 15;
        float4 v = *(const float4*)(kbase + (size_t)r * ld + seg * 4);
        float* dst = &kslab[r * 65 + seg * 4];
        dst[0] = v.x; dst[1] = v.y; dst[2] = v.z; dst[3] = v.w;
    }
    __syncthreads();
    int halfL = LQ >> 1;
    for (int li = threadIdx.x; li < halfL; li += 256) {
        int l = half * halfL + li;
        const float4* q = (const float4*)(Qp + (size_t)(b * LQ + l) * ld + h * 64);
        float qr[64];
        #pragma unroll
        for (int d4 = 0; d4 < 16; d4++) {
            float4 v = q[d4];
            qr[4 * d4] = v.x; qr[4 * d4 + 1] = v.y; qr[4 * d4 + 2] = v.z; qr[4 * d4 + 3] = v.w;
        }
        const int* ip = idx + l * U;
        float mx = -INFINITY, sm = 0.f;
        for (int s = 0; s < U; s++) {
            const float* kr = &kslab[ip[s] * 65];
            float acc = 0.f;
            #pragma unroll
            for (int d = 0; d < 64; d++) acc += qr[d] * kr[d];
            mx = fmaxf(mx, acc);
            sm += acc;
        }
        Mout[(size_t)bh * LQ + l] = mx - sm / (float)LK;
    }
}

// Fallback msamp if large dynamic-LDS attribute fails.
__global__ void msamp_k(const float* __restrict__ Qp, const float* __restrict__ Kp,
                        const int* __restrict__ idx, float* __restrict__ Mout,
                        int LQ, int LK, int U, int ld) {
    int t = blockIdx.x * 256 + threadIdx.x;
    int total = 16 * 8 * LQ * 4;
    if (t >= total) return;
    int p = t & 3;
    int rest = t >> 2;
    int l = rest % LQ;
    int h = (rest / LQ) & 7;
    int b = rest / (LQ * 8);
    const float4* q = (const float4*)(Qp + ((size_t)(b * LQ + l) * ld + h * 64));
    const float* kb = Kp + ((size_t)b * LK * ld + h * 64);
    float4 qr[16];
    #pragma unroll
    for (int d = 0; d < 16; d++) qr[d] = q[d];
    float mx = -INFINITY, sm = 0.f;
    for (int s = p; s < U; s += 4) {
        const float4* kr = (const float4*)(kb + (size_t)idx[l * U + s] * ld);
        float acc = 0.f;
        #pragma unroll
        for (int d = 0; d < 16; d++) {
            float4 kv = kr[d];
            acc += qr[d].x * kv.x + qr[d].y * kv.y + qr[d].z * kv.z + qr[d].w * kv.w;
        }
        mx = fmaxf(mx, acc);
        sm += acc;
    }
    mx = fmaxf(mx, __shfl_xor(mx, 1));
    mx = fmaxf(mx, __shfl_xor(mx, 2));
    sm += __shfl_xor(sm, 1);
    sm += __shfl_xor(sm, 2);
    if (p == 0)
        Mout[(size_t)((b * 8) + h) * LQ + l] = mx - sm / (float)LK;
}

// Parallel top-u per (b,h): iterative argmax in LDS, lowest-index tie-break.
__global__ __launch_bounds__(256) void topk_k(const float* __restrict__ M,
                                              int* __restrict__ top, int LQ, int u) {
    __shared__ float vals[512];
    __shared__ float rv[256];
    __shared__ int ri[256];
    int bh = blockIdx.x;
    int tid = threadIdx.x;
    const float* m = M + (size_t)bh * LQ;
    for (int l = tid; l < LQ; l += 256) vals[l] = m[l];
    __syncthreads();
    for (int j = 0; j < u; j++) {
        float best = -INFINITY;
        int bi = LQ;
        for (int l = tid; l < LQ; l += 256) {
            float v = vals[l];
            if (v > best) { best = v; bi = l; }
        }
        rv[tid] = best; ri[tid] = bi;
        __syncthreads();
        for (int s = 128; s > 0; s >>= 1) {
            if (tid < s) {
                float v2 = rv[tid + s]; int i2 = ri[tid + s];
                if (v2 > rv[tid] || (v2 == rv[tid] && i2 < ri[tid])) { rv[tid] = v2; ri[tid] = i2; }
            }
            __syncthreads();
        }
        int sel = ri[0];
        if (tid == 0) {
            top[bh * u + j] = sel;
            vals[sel] = -INFINITY;
        }
        __syncthreads();
    }
}

// vm[b,c] = mean over l of V[b,l,c]; parallel over l. grid (16 c-chunks, 16 b).
__global__ __launch_bounds__(256) void vmean_k(const float* __restrict__ Vp,
                                               float* __restrict__ vm, int LK, int ld) {
    __shared__ float red[8][33];
    int b = blockIdx.y;
    int c0 = blockIdx.x * 32;
    int ci = threadIdx.x & 31, g = threadIdx.x >> 5;
    const float* base = Vp + (size_t)b * LK * ld + c0 + ci;
    float s = 0.f;
    for (int l = g; l < LK; l += 8) s += base[(size_t)l * ld];
    red[g][ci] = s;
    __syncthreads();
    if (threadIdx.x < 32) {
        float t = 0.f;
        #pragma unroll
        for (int g2 = 0; g2 < 8; g2++) t += red[g2][threadIdx.x];
        vm[b * 512 + c0 + threadIdx.x] = t / (float)LK;
    }
}

// ctxb[b,l,c] = bf16(vm[b,c])
__global__ void ctx_fill_k(const float* __restrict__ vm, short* __restrict__ ctxb,
                           int LQ, int total) {
    int t = blockIdx.x * 256 + threadIdx.x;
    if (t >= total) return;
    int c = t % 512;
    int b = t / (512 * LQ);
    ctxb[t] = f2bf(vm[b * 512 + c]);
}

// Flash-style ProbSparse attention: one block per (b, h, u-half), 256 threads.
__global__ __launch_bounds__(256) void attn_flash_k(
    const float* __restrict__ Qp, const float* __restrict__ Kp, const float* __restrict__ Vp,
    const int* __restrict__ top, short* __restrict__ ctxb, int LQ, int LK, int u, int ld) {
    __shared__ float qs[18][64];
    __shared__ int ls[18];
    __shared__ float kv[64][65];
    __shared__ float sc[18][512];
    int bid = blockIdx.x;
    int chunk = bid & 1;  // 2 chunks per (b,h)
    int h = (bid >> 1) & 7;
    int b = bid >> 4;
    int CH = (u + 1) >> 1;
    int r0 = chunk * CH;
    int nr = min(CH, u - r0);
    int tid = threadIdx.x;
    int wave = tid >> 6, lane = tid & 63;

    if (tid < nr) ls[tid] = top[((b * 8) + h) * u + r0 + tid];
    __syncthreads();
    for (int t = tid; t < nr * 16; t += 256) {
        int r = t >> 4, seg = t & 15;
        float4 v = *(const float4*)(Qp + ((size_t)(b * LQ + ls[r])) * ld + h * 64 + seg * 4);
        float* dst = &qs[r][seg * 4];
        dst[0] = v.x; dst[1] = v.y; dst[2] = v.z; dst[3] = v.w;
    }

    int ntile = LK >> 6;
    const float* kbase = Kp + ((size_t)b * LK) * ld + h * 64;
    for (int T = 0; T < ntile; T++) {
        __syncthreads();
        #pragma unroll
        for (int it = 0; it < 4; it++) {
            int t = tid + it * 256;
            int kk = t >> 4, seg = t & 15;
            float4 v = *(const float4*)(kbase + (size_t)(T * 64 + kk) * ld + seg * 4);
            float* dst = &kv[kk][seg * 4];
            dst[0] = v.x; dst[1] = v.y; dst[2] = v.z; dst[3] = v.w;
        }
        __syncthreads();
        for (int p = tid; p < nr * 64; p += 256) {
            int r = p >> 6, kk = p & 63;
            float acc = 0.f;
            #pragma unroll
            for (int d = 0; d < 64; d++) acc += qs[r][d] * kv[kk][d];
            sc[r][T * 64 + kk] = acc * 0.125f;  // 1/sqrt(64)
        }
    }
    __syncthreads();
    for (int r = wave; r < nr; r += 4) {
        float mx = -INFINITY;
        for (int k = lane; k < LK; k += 64) mx = fmaxf(mx, sc[r][k]);
        #pragma unroll
        for (int o = 32; o > 0; o >>= 1) mx = fmaxf(mx, __shfl_xor(mx, o));
        float s = 0.f;
        for (int k = lane; k < LK; k += 64) {
            float e = expf(sc[r][k] - mx);
            sc[r][k] = e;
            s += e;
        }
        #pragma unroll
        for (int o = 32; o > 0; o >>= 1) s += __shfl_xor(s, o);
        float inv = 1.0f / s;
        for (int k = lane; k < LK; k += 64) sc[r][k] *= inv;
    }
    float acc[5];
    #pragma unroll
    for (int i = 0; i < 5; i++) acc[i] = 0.f;
    const float* vbase = Vp + ((size_t)b * LK) * ld + h * 64;
    for (int T = 0; T < ntile; T++) {
        __syncthreads();
        #pragma unroll
        for (int it = 0; it < 4; it++) {
            int t = tid + it * 256;
            int kk = t >> 4, seg = t & 15;
            float4 v = *(const float4*)(vbase + (size_t)(T * 64 + kk) * ld + seg * 4);
            float* dst = &kv[kk][seg * 4];
            dst[0] = v.x; dst[1] = v.y; dst[2] = v.z; dst[3] = v.w;
        }
        __syncthreads();
        int ri = 0;
        for (int r = wave; r < nr; r += 4, ri++) {
            float a = 0.f;
            #pragma unroll
            for (int kk = 0; kk < 64; kk++) a += sc[r][T * 64 + kk] * kv[kk][lane];
            acc[ri] += a;
        }
    }
    int ri = 0;
    for (int r = wave; r < nr; r += 4, ri++)
        ctxb[((size_t)(b * LQ + ls[r])) * 512 + h * 64 + lane] = f2bf(acc[ri]);
}

// per-row layer norm, D=512; optional bf16 mirror
__global__ __launch_bounds__(256) void ln_k(const float* __restrict__ in,
                                            float* __restrict__ out, short* __restrict__ outb) {
    __shared__ float red[256];
    int r = blockIdx.x;
    int tid = threadIdx.x;
    const float* x = in + (size_t)r * 512;
    float a = x[tid], b = x[tid + 256];
    red[tid] = a + b;
    __syncthreads();
    for (int s = 128; s > 0; s >>= 1) {
        if (tid < s) red[tid] += red[tid + s];
        __syncthreads();
    }
    float mu = red[0] / 512.f;
    __syncthreads();
    float d1 = a - mu, d2 = b - mu;
    red[tid] = d1 * d1 + d2 * d2;
    __syncthreads();
    for (int s = 128; s > 0; s >>= 1) {
        if (tid < s) red[tid] += red[tid + s];
        __syncthreads();
    }
    float inv = 1.0f / sqrtf(red[0] / 512.f + 1e-5f);
    float v1 = d1 * inv, v2 = d2 * inv;
    out[(size_t)r * 512 + tid] = v1;
    out[(size_t)r * 512 + tid + 256] = v2;
    if (outb) {
        outb[(size_t)r * 512 + tid] = f2bf(v1);
        outb[(size_t)r * 512 + tid + 256] = f2bf(v2);
    }
}

// circular-pad im2col -> bf16
__global__ void xcat_k(const float* __restrict__ x, short* __restrict__ xc, int L, int total) {
    int t = blockIdx.x * 256 + threadIdx.x;
    if (t >= total) return;
    int i = t % 512;
    int h = (t / 512) % 3;
    int bt = t / 1536;
    int tt = bt % L;
    int b = bt / L;
    int src = (tt + h - 1 + L) % L;
    xc[t] = f2bf(x[(size_t)(b * L + src) * 512 + i]);
}

// bn stage 1: per-chunk per-channel sum/sumsq, coalesced row reads. grid=128.
__global__ __launch_bounds__(256) void bnpart_k(const float* __restrict__ y,
                                                float* __restrict__ ps, float* __restrict__ pq,
                                                int rows) {
    int chunk = blockIdx.x;
    int rpc = rows >> 7;
    int r0 = chunk * rpc;
    int tid = threadIdx.x;
    float s0 = 0.f, s1 = 0.f, q0 = 0.f, q1 = 0.f;
    for (int r = r0; r < r0 + rpc; r++) {
        float a = y[(size_t)r * 512 + tid];
        float b = y[(size_t)r * 512 + tid + 256];
        s0 += a; q0 += a * a;
        s1 += b; q1 += b * b;
    }
    ps[chunk * 512 + tid] = s0;
    ps[chunk * 512 + tid + 256] = s1;
    pq[chunk * 512 + tid] = q0;
    pq[chunk * 512 + tid + 256] = q1;
}

// bn stage 2: mu = s/n; var = q/n - mu^2.
__global__ void bnfin_k(const float* __restrict__ ps, const float* __restrict__ pq,
                        float* __restrict__ mu, float* __restrict__ var, int rows) {
    int o = blockIdx.x * 256 + threadIdx.x;
    if (o >= 512) return;
    float s = 0.f, q = 0.f;
    for (int c = 0; c < 128; c++) {
        s += ps[c * 512 + o];
        q += pq[c * 512 + o];
    }
    float m = s / (float)rows;
    mu[o] = m;
    var[o] = q / (float)rows - m * m;
}

// normalize -> max-pool(3,2,pad1) -> elu; writes fp32 + bf16 mirror
__global__ void elu_pool_k(const float* __restrict__ y, const float* __restrict__ mu,
                           const float* __restrict__ var, float* __restrict__ out,
                           short* __restrict__ outb, int L, int total) {
    int t = blockIdx.x * 256 + threadIdx.x;
    if (t >= total) return;
    int o = t % 512;
    int tp = (t / 512) % (L / 2);
    int b = t / (512 * (L / 2));
    float mm = mu[o];
    float inv = 1.0f / sqrtf(var[o] + 1e-5f);
    float m = -INFINITY;
    #pragma unroll
    for (int dt = 0; dt < 3; dt++) {
        int tt = 2 * tp - 1 + dt;
        if (tt < 0 || tt >= L) continue;
        float v = (y[(size_t)(b * L + tt) * 512 + o] - mm) * inv;
        m = fmaxf(m, v);
    }
    float r = m > 0.f ? m : expm1f(m);
    out[t] = r;
    outb[t] = f2bf(r);
}

// out[r] = dot(x[r,:512], w) + b
__global__ void final_k(const float* __restrict__ x, const float* __restrict__ w,
                        const float* __restrict__ bb, float* __restrict__ out, int rows) {
    int gid = blockIdx.x * 256 + threadIdx.x;
    int wid = gid >> 6;
    int lane = gid & 63;
    if (wid >= rows) return;
    const float* xr = x + (size_t)wid * 512;
    float acc = 0.f;
    for (int k = lane; k < 512; k += 64) acc += xr[k] * w[k];
    for (int off = 32; off > 0; off >>= 1) acc += __shfl_down(acc, off);
    if (lane == 0) out[wid] = acc + bb[0];
}

// ---------------------------------------------------------------------------
// Host driver
// ---------------------------------------------------------------------------

static inline int iceil_log(int L) { return (int)ceil(log((double)L)); }
static inline int imin(int a, int b) { return a < b ? a : b; }

extern "C" void kernel_launch(void* const* d_in, const int* in_sizes, int n_in,
                              void* d_out, int out_size, void* d_ws, size_t ws_size,
                              hipStream_t stream) {
    const float* IN  = (const float*)d_in[0];
    const float* Wq  = (const float*)d_in[1];
    const float* bq  = (const float*)d_in[2];
    const float* Wk  = (const float*)d_in[3];
    const float* bk  = (const float*)d_in[4];
    const float* Wv  = (const float*)d_in[5];
    const float* bv  = (const float*)d_in[6];
    const float* Wo  = (const float*)d_in[7];
    const float* bo  = (const float*)d_in[8];
    const float* ew1 = (const float*)d_in[9];
    const float* eb1 = (const float*)d_in[10];
    const float* ew2 = (const float*)d_in[11];
    const float* eb2 = (const float*)d_in[12];
    const float* dw1 = (const float*)d_in[13];
    const float* db1 = (const float*)d_in[14];
    const float* dw2 = (const float*)d_in[15];
    const float* db2 = (const float*)d_in[16];
    const float* DW  = (const float*)d_in[17];
    const float* db  = (const float*)d_in[18];
    const float* ow  = (const float*)d_in[19];
    const float* ob  = (const float*)d_in[20];
    float* OUT = (float*)d_out;

    float* ws = (float*)d_ws;
    size_t off = 0;
    auto alloc = [&](size_t n) { float* p = ws + off; off += n; return p; };
    float* PE   = alloc(4194304);
    short* PEb  = (short*)alloc(2097152);
    float* QKV  = alloc(12582912);
    float* CTX  = alloc(4194304);
    short* CTXb = (short*)alloc(2097152);
    float* T1   = alloc(4194304);
    short* T1b  = (short*)alloc(2097152);
    float* XLN  = alloc(4194304);
    short* XLNb = (short*)alloc(2097152);
    float* T2   = alloc(4194304);
    short* T2b  = (short*)alloc(2097152);
    float* T3   = alloc(4194304);
    short* HIDb = (short*)alloc(8388608);
    float* D1   = alloc(2097152);
    short* D1b  = (short*)alloc(1048576);
    float* D2   = alloc(1048576);
    short* D2b  = (short*)alloc(524288);
    short* Ebb  = (short*)alloc(262144);
    float* Ebf  = alloc(524288);
    float* MB   = alloc(65536);
    float* VM   = alloc(8192);
    float* MU   = alloc(512);
    float* VARb = alloc(512);
    float* BQKV = alloc(1536);
    float* PS   = alloc(65536);
    float* PQ   = alloc(65536);
    int* IDX  = (int*)alloc(17920);
    int* TOPB = (int*)alloc(4480);
    short* WqkvT = (short*)alloc(393216);
    short* WoT   = (short*)alloc(131072);
    short* ew1T  = (short*)alloc(524288);
    short* ew2T  = (short*)alloc(524288);
    short* dw1T  = (short*)alloc(524288);
    short* dw2T  = (short*)alloc(524288);
    short* W2T   = (short*)alloc(393216);
    (void)ws_size; (void)n_in; (void)in_sizes; (void)out_size;

    static_assert(512 * 65 * 4 == 133120, "");
    hipError_t attr_ok = hipFuncSetAttribute(
        (const void*)msamp_lds_k, hipFuncAttributeMaxDynamicSharedMemorySize, 133120);

    // Auto-select tile: 128x128 when the grid stays >= 256 blocks (1/CU),
    // else 64x64 (better oversubscription for small shapes). K-loop order
    // identical in both -> bit-identical C.
    auto gemm = [&](const short* A, const short* Bt, const float* bias, const float* res,
                    float* C32, short* C16, int M, int N, int K, int relu, int ldC) {
        if ((M & 127) == 0 && (N & 127) == 0 && (M >> 7) * (N >> 7) >= 256) {
            gemm128_k<<<(N / 128) * (M / 128), 256, 0, stream>>>(A, Bt, bias, res, C32, C16,
                                                                 M, N, K, relu, ldC);
        } else {
            gemm64_k<<<(N / 64) * (M / 64), 256, 0, stream>>>(A, Bt, bias, res, C32, C16,
                                                              M, N, K, relu, ldC);
        }
    };
    auto tr = [&](const float* W, short* Wt, int K, int N) {
        dim3 g(N / 32, K / 32);
        transpose_bf16_k<<<g, 256, 0, stream>>>(W, Wt, K, N);
    };

    auto attn = [&](const short* qinb, const short* kvinb, const float* resp,
                    float* out32, short* out16, int LQ, int LK, int ikey) {
        int Mq = 16 * LQ, Mk = 16 * LK;
        const int ld = 1536;
        float* Qp = QKV;
        float* Kp = QKV + 512;
        float* Vp = QKV + 1024;
        if (qinb == kvinb) {
            gemm(qinb, WqkvT, BQKV, nullptr, QKV, nullptr, Mq, 1536, 512, 0, ld);
        } else {
            gemm(qinb, WqkvT, BQKV, nullptr, QKV, nullptr, Mq, 512, 512, 0, ld);
            gemm(kvinb, WqkvT + 512 * 512, BQKV + 512, nullptr, QKV + 512, nullptr,
                 Mk, 1024, 512, 0, ld);
        }
        int U = imin(5 * iceil_log(LK), LK);
        int u = imin(5 * iceil_log(LQ), LQ);
        unsigned rk0, rk1;
        threefry2x32(0u, 42u, 0u, (unsigned)ikey, rk0, rk1);
        int size = LQ * U;
        ridx_k<<<(size + 255) / 256, 256, 0, stream>>>(rk0, rk1, size, (unsigned)(LK - 1), IDX);
        size_t shbytes = (size_t)LK * 65 * 4;
        if (attr_ok == hipSuccess || shbytes <= 65536) {
            msamp_lds_k<<<16 * 8 * 2, 256, shbytes, stream>>>(Qp, Kp, IDX, MB, LQ, LK, U, ld);
        } else {
            int totM = 16 * 8 * LQ * 4;
            msamp_k<<<(totM + 255) / 256, 256, 0, stream>>>(Qp, Kp, IDX, MB, LQ, LK, U, ld);
        }
        topk_k<<<128, 256, 0, stream>>>(MB, TOPB, LQ, u);
        vmean_k<<<dim3(16, 16), 256, 0, stream>>>(Vp, VM, LK, ld);
        int totC = 16 * LQ * 512;
        ctx_fill_k<<<(totC + 255) / 256, 256, 0, stream>>>(VM, CTXb, LQ, totC);
        attn_flash_k<<<16 * 8 * 2, 256, 0, stream>>>(Qp, Kp, Vp, TOPB, CTXb, LQ, LK, u, ld);
        gemm(CTXb, WoT, bo, resp, out32, out16, Mq, 512, 512, 0, 512);
    };

    auto encoder = [&](const short* Xb, const float* X, int L, int ikey, float* OUTenc) {
        int M = 16 * L;
        attn(Xb, Xb, X, T1, nullptr, L, L, ikey);
        ln_k<<<M, 256, 0, stream>>>(T1, XLN, XLNb);
        gemm(XLNb, ew1T, eb1, nullptr, nullptr, HIDb, M, 2048, 512, 1, 2048);
        gemm(HIDb, ew2T, eb2, XLN, T2, nullptr, M, 512, 2048, 0, 512);
        ln_k<<<M, 256, 0, stream>>>(T2, OUTenc, nullptr);
    };

    auto distill = [&](const float* X, int L, float* OUTd, short* OUTdb) {
        int M = 16 * L;
        int tot = M * 1536;
        xcat_k<<<(tot + 255) / 256, 256, 0, stream>>>(X, HIDb, L, tot);
        gemm(HIDb, W2T, db, nullptr, CTX, nullptr, M, 512, 1536, 0, 512);
        bnpart_k<<<128, 256, 0, stream>>>(CTX, PS, PQ, M);
        bnfin_k<<<2, 256, 0, stream>>>(PS, PQ, MU, VARb, M);
        int toto = 16 * (L / 2) * 512;
        elu_pool_k<<<(toto + 255) / 256, 256, 0, stream>>>(CTX, MU, VARb, OUTd, OUTdb, L, toto);
    };

    // --- weight conversion (once per launch) ---
    tr(Wq, WqkvT, 512, 512);
    tr(Wk, WqkvT + 512 * 512, 512, 512);
    tr(Wv, WqkvT + 1024 * 512, 512, 512);
    tr(Wo, WoT, 512, 512);
    tr(ew1, ew1T, 512, 2048);
    tr(ew2, ew2T, 2048, 512);
    tr(dw1, dw1T, 512, 2048);
    tr(dw2, dw2T, 2048, 512);
    w2t_k<<<(786432 + 255) / 256, 256, 0, stream>>>(DW, W2T, 786432);
    bcat_k<<<6, 256, 0, stream>>>(bq, bk, bv, BQKV);

    // --- forward ---
    int totPE = 16 * 512 * 512;
    pe_add_k<<<(totPE + 255) / 256, 256, 0, stream>>>(IN, PE, PEb, totPE);

    encoder(PEb, PE, 512, 0, T3); distill(T3, 512, D1, D1b);
    encoder(D1b, D1, 256, 1, T3); distill(T3, 256, D2, D2b);
    encoder(D2b, D2, 128, 2, T3); distill(T3, 128, Ebf, Ebb);

    attn(PEb, PEb, PE, T1, T1b, 512, 512, 3);   // out1 = dec_inp + attn
    attn(T1b, Ebb, T1, T2, T2b, 512, 64, 4);    // out2 = out1 + cross-attn
    gemm(T2b, dw1T, db1, nullptr, nullptr, HIDb, 8192, 2048, 512, 1, 2048);
    gemm(HIDb, dw2T, db2, T2, T3, nullptr, 8192, 512, 2048, 0, 512);
    final_k<<<(8192 * 64) / 256, 256, 0, stream>>>(T3, ow, ob, OUT, 8192);
}

// Round 14
// 1718.923 us; speedup vs baseline: 1.0083x; 1.0083x over previous
//
#include <hip/hip_runtime.h>
#include <cstdint>
#include <cmath>

// ---------------------------------------------------------------------------
// Informer forward. Round 14: REVERT R13 tile routing (128-tile at N=512 gave
// 1 block/CU -> latency-bound, 62.7->84us regression; blocks/CU beats
// per-block pipe balance in this regime). Keep R12 routing; change gemm64
// BK 32->64: halves barrier count on K=2048/1536 GEMMs, same k-order ->
// bit-identical C. jax.random via threefry2x32 (H2, verified R1).
// ---------------------------------------------------------------------------

#define HD __host__ __device__

typedef short short8 __attribute__((ext_vector_type(8)));
typedef float float4v __attribute__((ext_vector_type(4)));

__device__ inline short f2bf(float f) {  // RNE
    unsigned u = __float_as_uint(f);
    unsigned r = u + 0x7FFFu + ((u >> 16) & 1u);
    return (short)(r >> 16);
}

HD inline unsigned rotl32(unsigned x, int r) { return (x << r) | (x >> (32 - r)); }
HD inline void tfround(unsigned& x0, unsigned& x1, int r) {
    x0 += x1; x1 = rotl32(x1, r); x1 ^= x0;
}
HD inline void threefry2x32(unsigned k0, unsigned k1, unsigned c0, unsigned c1,
                            unsigned& o0, unsigned& o1) {
    unsigned ks2 = k0 ^ k1 ^ 0x1BD11BDAu;
    unsigned x0 = c0 + k0, x1 = c1 + k1;
    tfround(x0, x1, 13); tfround(x0, x1, 15); tfround(x0, x1, 26); tfround(x0, x1, 6);
    x0 += k1; x1 += ks2 + 1u;
    tfround(x0, x1, 17); tfround(x0, x1, 29); tfround(x0, x1, 16); tfround(x0, x1, 24);
    x0 += ks2; x1 += k0 + 2u;
    tfround(x0, x1, 13); tfround(x0, x1, 15); tfround(x0, x1, 26); tfround(x0, x1, 6);
    x0 += k0; x1 += k1 + 3u;
    tfround(x0, x1, 17); tfround(x0, x1, 29); tfround(x0, x1, 16); tfround(x0, x1, 24);
    x0 += k1; x1 += ks2 + 4u;
    tfround(x0, x1, 13); tfround(x0, x1, 15); tfround(x0, x1, 26); tfround(x0, x1, 6);
    x0 += ks2; x1 += k0 + 5u;
    o0 = x0; o1 = x1;
}

// ---------------------------------------------------------------------------
// Kernels
// ---------------------------------------------------------------------------

// out = in + PE; outb = bf16(out)
__global__ void pe_add_k(const float* __restrict__ in, float* __restrict__ out,
                         short* __restrict__ outb, int total) {
    int t = blockIdx.x * 256 + threadIdx.x;
    if (t >= total) return;
    int d = t % 512;
    int l = (t / 512) % 512;
    float i2 = (float)(d & ~1);
    float div = expf(i2 * (-0.017988946039016f));  // -ln(10000)/512
    float ang = (float)l * div;
    float v = (d & 1) ? cosf(ang) : sinf(ang);
    float r = in[t] + v;
    out[t] = r;
    outb[t] = f2bf(r);
}

// fp32 [K][N] -> bf16 [N][K] via 32x32 LDS tile
__global__ __launch_bounds__(256) void transpose_bf16_k(const float* __restrict__ in,
                                                        short* __restrict__ out, int K, int N) {
    __shared__ float tile[32][33];
    int k0 = blockIdx.y * 32, n0 = blockIdx.x * 32;
    int c = threadIdx.x & 31, r0 = threadIdx.x >> 5;
    for (int rr = r0; rr < 32; rr += 8)
        tile[rr][c] = in[(size_t)(k0 + rr) * N + n0 + c];
    __syncthreads();
    for (int rr = r0; rr < 32; rr += 8)
        out[(size_t)(n0 + rr) * K + k0 + c] = f2bf(tile[c][rr]);
}

// dist_w (O,I,H) -> bf16 W2T[o][h*512+i]
__global__ void w2t_k(const float* __restrict__ dw, short* __restrict__ out, int total) {
    int t = blockIdx.x * 256 + threadIdx.x;
    if (t >= total) return;
    int kk = t % 1536;
    int o = t / 1536;
    int h = kk / 512, i = kk % 512;
    out[t] = f2bf(dw[(size_t)o * 1536 + i * 3 + h]);
}

// concat biases bq|bk|bv -> bqkv[1536]
__global__ void bcat_k(const float* __restrict__ b0, const float* __restrict__ b1,
                       const float* __restrict__ b2, float* __restrict__ out) {
    int t = blockIdx.x * 256 + threadIdx.x;
    if (t >= 1536) return;
    out[t] = (t < 512) ? b0[t] : (t < 1024 ? b1[t - 512] : b2[t - 1024]);
}

__device__ inline void swizzle_bid(int bid, int nbx, int nby, int& bm, int& bn) {
    if ((nby & 7) == 0) {
        int stripe = nby >> 3;
        int x = bid & 7, w = bid >> 3;
        bn = w % nbx;
        bm = x * stripe + w / nbx;
    } else {
        bn = bid % nbx;
        bm = bid / nbx;
    }
}

// bf16 MFMA GEMM, 128x128 tile, BK=32; A bf16 [M][K], Bt bf16 [N][K].
__global__ __launch_bounds__(256) void gemm128_k(
    const short* __restrict__ A, const short* __restrict__ Bt,
    const float* __restrict__ bias, const float* __restrict__ res,
    float* __restrict__ C32, short* __restrict__ C16,
    int M, int N, int K, int relu, int ldC) {
    __shared__ short As[128 * 40];
    __shared__ short Bs[128 * 40];
    int tid = threadIdx.x;
    int wave = tid >> 6, lane = tid & 63;
    int wy = wave >> 1, wx = wave & 1;
    int rl = lane & 15, quad = lane >> 4;
    int bm, bn;
    swizzle_bid(blockIdx.x, N >> 7, M >> 7, bm, bn);
    bm <<= 7; bn <<= 7;

    float4v acc[4][4];
    #pragma unroll
    for (int i = 0; i < 4; i++)
        #pragma unroll
        for (int j = 0; j < 4; j++) acc[i][j] = (float4v){0.f, 0.f, 0.f, 0.f};

    for (int k0 = 0; k0 < K; k0 += 32) {
        #pragma unroll
        for (int it = 0; it < 2; it++) {
            int c = tid + it * 256;
            int row = c >> 2, seg = c & 3;
            *(float4*)&As[row * 40 + seg * 8] =
                *(const float4*)(A + (size_t)(bm + row) * K + k0 + seg * 8);
        }
        #pragma unroll
        for (int it = 0; it < 2; it++) {
            int c = tid + it * 256;
            int row = c >> 2, seg = c & 3;
            *(float4*)&Bs[row * 40 + seg * 8] =
                *(const float4*)(Bt + (size_t)(bn + row) * K + k0 + seg * 8);
        }
        __syncthreads();
        short8 a[4], b[4];
        #pragma unroll
        for (int i = 0; i < 4; i++)
            a[i] = *(const short8*)&As[(wy * 64 + i * 16 + rl) * 40 + quad * 8];
        #pragma unroll
        for (int j = 0; j < 4; j++)
            b[j] = *(const short8*)&Bs[(wx * 64 + j * 16 + rl) * 40 + quad * 8];
        #pragma unroll
        for (int i = 0; i < 4; i++)
            #pragma unroll
            for (int j = 0; j < 4; j++)
                acc[i][j] = __builtin_amdgcn_mfma_f32_16x16x32_bf16(a[i], b[j], acc[i][j], 0, 0, 0);
        __syncthreads();
    }
    #pragma unroll
    for (int i = 0; i < 4; i++) {
        #pragma unroll
        for (int r = 0; r < 4; r++) {
            int gm = bm + wy * 64 + i * 16 + quad * 4 + r;
            #pragma unroll
            for (int j = 0; j < 4; j++) {
                int gn = bn + wx * 64 + j * 16 + rl;
                float v = acc[i][j][r];
                if (bias) v += bias[gn];
                if (relu) v = fmaxf(v, 0.f);
                if (res) v += res[(size_t)gm * ldC + gn];
                if (C32) C32[(size_t)gm * ldC + gn] = v;
                if (C16) C16[(size_t)gm * ldC + gn] = f2bf(v);
            }
        }
    }
}

// 64x64-tile variant, BK=64 (R14: halves barrier count; per-accumulator
// k-order unchanged -> bit-identical). 4 waves, each 16x64. Requires K%64==0.
__global__ __launch_bounds__(256) void gemm64_k(
    const short* __restrict__ A, const short* __restrict__ Bt,
    const float* __restrict__ bias, const float* __restrict__ res,
    float* __restrict__ C32, short* __restrict__ C16,
    int M, int N, int K, int relu, int ldC) {
    __shared__ short As[64 * 72];
    __shared__ short Bs[64 * 72];
    int tid = threadIdx.x;
    int wave = tid >> 6, lane = tid & 63;
    int rl = lane & 15, quad = lane >> 4;
    int bm, bn;
    swizzle_bid(blockIdx.x, N >> 6, M >> 6, bm, bn);
    bm <<= 6; bn <<= 6;

    float4v acc[4];
    #pragma unroll
    for (int j = 0; j < 4; j++) acc[j] = (float4v){0.f, 0.f, 0.f, 0.f};

    for (int k0 = 0; k0 < K; k0 += 64) {
        #pragma unroll
        for (int it = 0; it < 2; it++) {
            int c = tid + it * 256;
            int row = c >> 3, seg = c & 7;
            *(float4*)&As[row * 72 + seg * 8] =
                *(const float4*)(A + (size_t)(bm + row) * K + k0 + seg * 8);
            *(float4*)&Bs[row * 72 + seg * 8] =
                *(const float4*)(Bt + (size_t)(bn + row) * K + k0 + seg * 8);
        }
        __syncthreads();
        #pragma unroll
        for (int ks = 0; ks < 64; ks += 32) {
            short8 a = *(const short8*)&As[(wave * 16 + rl) * 72 + ks + quad * 8];
            short8 b[4];
            #pragma unroll
            for (int j = 0; j < 4; j++)
                b[j] = *(const short8*)&Bs[(j * 16 + rl) * 72 + ks + quad * 8];
            #pragma unroll
            for (int j = 0; j < 4; j++)
                acc[j] = __builtin_amdgcn_mfma_f32_16x16x32_bf16(a, b[j], acc[j], 0, 0, 0);
        }
        __syncthreads();
    }
    #pragma unroll
    for (int r = 0; r < 4; r++) {
        int gm = bm + wave * 16 + quad * 4 + r;
        #pragma unroll
        for (int j = 0; j < 4; j++) {
            int gn = bn + j * 16 + rl;
            float v = acc[j][r];
            if (bias) v += bias[gn];
            if (relu) v = fmaxf(v, 0.f);
            if (res) v += res[(size_t)gm * ldC + gn];
            if (C32) C32[(size_t)gm * ldC + gn] = v;
            if (C16) C16[(size_t)gm * ldC + gn] = f2bf(v);
        }
    }
}

// idx[j] = threefry(rkey, (j, j+size)).second & mask   (H2, verified R1)
__global__ void ridx_k(unsigned k0, unsigned k1, int size, unsigned mask, int* __restrict__ idx) {
    int j = blockIdx.x * 256 + threadIdx.x;
    if (j >= size) return;
    unsigned o0, o1;
    threefry2x32(k0, k1, (unsigned)j, (unsigned)(j + size), o0, o1);
    idx[j] = (int)(o1 & mask);
}

// msamp, K-slab in LDS. One block per (b, h, l-half); grid 16*8*2 = 256.
extern __shared__ float kslab[];
__global__ __launch_bounds__(256) void msamp_lds_k(
    const float* __restrict__ Qp, const float* __restrict__ Kp,
    const int* __restrict__ idx, float* __restrict__ Mout,
    int LQ, int LK, int U, int ld) {
    int bid = blockIdx.x;
    int half = bid & 1;
    int bh = bid >> 1;
    int h = bh & 7, b = bh >> 3;
    const float* kbase = Kp + (size_t)b * LK * ld + h * 64;
    for (int t = threadIdx.x; t < LK * 16; t += 256) {
        int r = t >> 4, seg = t & 15;
        float4 v = *(const float4*)(kbase + (size_t)r * ld + seg * 4);
        float* dst = &kslab[r * 65 + seg * 4];
        dst[0] = v.x; dst[1] = v.y; dst[2] = v.z; dst[3] = v.w;
    }
    __syncthreads();
    int halfL = LQ >> 1;
    for (int li = threadIdx.x; li < halfL; li += 256) {
        int l = half * halfL + li;
        const float4* q = (const float4*)(Qp + (size_t)(b * LQ + l) * ld + h * 64);
        float qr[64];
        #pragma unroll
        for (int d4 = 0; d4 < 16; d4++) {
            float4 v = q[d4];
            qr[4 * d4] = v.x; qr[4 * d4 + 1] = v.y; qr[4 * d4 + 2] = v.z; qr[4 * d4 + 3] = v.w;
        }
        const int* ip = idx + l * U;
        float mx = -INFINITY, sm = 0.f;
        for (int s = 0; s < U; s++) {
            const float* kr = &kslab[ip[s] * 65];
            float acc = 0.f;
            #pragma unroll
            for (int d = 0; d < 64; d++) acc += qr[d] * kr[d];
            mx = fmaxf(mx, acc);
            sm += acc;
        }
        Mout[(size_t)bh * LQ + l] = mx - sm / (float)LK;
    }
}

// Fallback msamp if large dynamic-LDS attribute fails.
__global__ void msamp_k(const float* __restrict__ Qp, const float* __restrict__ Kp,
                        const int* __restrict__ idx, float* __restrict__ Mout,
                        int LQ, int LK, int U, int ld) {
    int t = blockIdx.x * 256 + threadIdx.x;
    int total = 16 * 8 * LQ * 4;
    if (t >= total) return;
    int p = t & 3;
    int rest = t >> 2;
    int l = rest % LQ;
    int h = (rest / LQ) & 7;
    int b = rest / (LQ * 8);
    const float4* q = (const float4*)(Qp + ((size_t)(b * LQ + l) * ld + h * 64));
    const float* kb = Kp + ((size_t)b * LK * ld + h * 64);
    float4 qr[16];
    #pragma unroll
    for (int d = 0; d < 16; d++) qr[d] = q[d];
    float mx = -INFINITY, sm = 0.f;
    for (int s = p; s < U; s += 4) {
        const float4* kr = (const float4*)(kb + (size_t)idx[l * U + s] * ld);
        float acc = 0.f;
        #pragma unroll
        for (int d = 0; d < 16; d++) {
            float4 kv = kr[d];
            acc += qr[d].x * kv.x + qr[d].y * kv.y + qr[d].z * kv.z + qr[d].w * kv.w;
        }
        mx = fmaxf(mx, acc);
        sm += acc;
    }
    mx = fmaxf(mx, __shfl_xor(mx, 1));
    mx = fmaxf(mx, __shfl_xor(mx, 2));
    sm += __shfl_xor(sm, 1);
    sm += __shfl_xor(sm, 2);
    if (p == 0)
        Mout[(size_t)((b * 8) + h) * LQ + l] = mx - sm / (float)LK;
}

// Parallel top-u per (b,h): iterative argmax in LDS, lowest-index tie-break.
__global__ __launch_bounds__(256) void topk_k(const float* __restrict__ M,
                                              int* __restrict__ top, int LQ, int u) {
    __shared__ float vals[512];
    __shared__ float rv[256];
    __shared__ int ri[256];
    int bh = blockIdx.x;
    int tid = threadIdx.x;
    const float* m = M + (size_t)bh * LQ;
    for (int l = tid; l < LQ; l += 256) vals[l] = m[l];
    __syncthreads();
    for (int j = 0; j < u; j++) {
        float best = -INFINITY;
        int bi = LQ;
        for (int l = tid; l < LQ; l += 256) {
            float v = vals[l];
            if (v > best) { best = v; bi = l; }
        }
        rv[tid] = best; ri[tid] = bi;
        __syncthreads();
        for (int s = 128; s > 0; s >>= 1) {
            if (tid < s) {
                float v2 = rv[tid + s]; int i2 = ri[tid + s];
                if (v2 > rv[tid] || (v2 == rv[tid] && i2 < ri[tid])) { rv[tid] = v2; ri[tid] = i2; }
            }
            __syncthreads();
        }
        int sel = ri[0];
        if (tid == 0) {
            top[bh * u + j] = sel;
            vals[sel] = -INFINITY;
        }
        __syncthreads();
    }
}

// vm[b,c] = mean over l of V[b,l,c]; parallel over l. grid (16 c-chunks, 16 b).
__global__ __launch_bounds__(256) void vmean_k(const float* __restrict__ Vp,
                                               float* __restrict__ vm, int LK, int ld) {
    __shared__ float red[8][33];
    int b = blockIdx.y;
    int c0 = blockIdx.x * 32;
    int ci = threadIdx.x & 31, g = threadIdx.x >> 5;
    const float* base = Vp + (size_t)b * LK * ld + c0 + ci;
    float s = 0.f;
    for (int l = g; l < LK; l += 8) s += base[(size_t)l * ld];
    red[g][ci] = s;
    __syncthreads();
    if (threadIdx.x < 32) {
        float t = 0.f;
        #pragma unroll
        for (int g2 = 0; g2 < 8; g2++) t += red[g2][threadIdx.x];
        vm[b * 512 + c0 + threadIdx.x] = t / (float)LK;
    }
}

// ctxb[b,l,c] = bf16(vm[b,c])
__global__ void ctx_fill_k(const float* __restrict__ vm, short* __restrict__ ctxb,
                           int LQ, int total) {
    int t = blockIdx.x * 256 + threadIdx.x;
    if (t >= total) return;
    int c = t % 512;
    int b = t / (512 * LQ);
    ctxb[t] = f2bf(vm[b * 512 + c]);
}

// Flash-style ProbSparse attention: one block per (b, h, u-half), 256 threads.
__global__ __launch_bounds__(256) void attn_flash_k(
    const float* __restrict__ Qp, const float* __restrict__ Kp, const float* __restrict__ Vp,
    const int* __restrict__ top, short* __restrict__ ctxb, int LQ, int LK, int u, int ld) {
    __shared__ float qs[18][64];
    __shared__ int ls[18];
    __shared__ float kv[64][65];
    __shared__ float sc[18][512];
    int bid = blockIdx.x;
    int chunk = bid & 1;  // 2 chunks per (b,h)
    int h = (bid >> 1) & 7;
    int b = bid >> 4;
    int CH = (u + 1) >> 1;
    int r0 = chunk * CH;
    int nr = min(CH, u - r0);
    int tid = threadIdx.x;
    int wave = tid >> 6, lane = tid & 63;

    if (tid < nr) ls[tid] = top[((b * 8) + h) * u + r0 + tid];
    __syncthreads();
    for (int t = tid; t < nr * 16; t += 256) {
        int r = t >> 4, seg = t & 15;
        float4 v = *(const float4*)(Qp + ((size_t)(b * LQ + ls[r])) * ld + h * 64 + seg * 4);
        float* dst = &qs[r][seg * 4];
        dst[0] = v.x; dst[1] = v.y; dst[2] = v.z; dst[3] = v.w;
    }

    int ntile = LK >> 6;
    const float* kbase = Kp + ((size_t)b * LK) * ld + h * 64;
    for (int T = 0; T < ntile; T++) {
        __syncthreads();
        #pragma unroll
        for (int it = 0; it < 4; it++) {
            int t = tid + it * 256;
            int kk = t >> 4, seg = t & 15;
            float4 v = *(const float4*)(kbase + (size_t)(T * 64 + kk) * ld + seg * 4);
            float* dst = &kv[kk][seg * 4];
            dst[0] = v.x; dst[1] = v.y; dst[2] = v.z; dst[3] = v.w;
        }
        __syncthreads();
        for (int p = tid; p < nr * 64; p += 256) {
            int r = p >> 6, kk = p & 63;
            float acc = 0.f;
            #pragma unroll
            for (int d = 0; d < 64; d++) acc += qs[r][d] * kv[kk][d];
            sc[r][T * 64 + kk] = acc * 0.125f;  // 1/sqrt(64)
        }
    }
    __syncthreads();
    for (int r = wave; r < nr; r += 4) {
        float mx = -INFINITY;
        for (int k = lane; k < LK; k += 64) mx = fmaxf(mx, sc[r][k]);
        #pragma unroll
        for (int o = 32; o > 0; o >>= 1) mx = fmaxf(mx, __shfl_xor(mx, o));
        float s = 0.f;
        for (int k = lane; k < LK; k += 64) {
            float e = expf(sc[r][k] - mx);
            sc[r][k] = e;
            s += e;
        }
        #pragma unroll
        for (int o = 32; o > 0; o >>= 1) s += __shfl_xor(s, o);
        float inv = 1.0f / s;
        for (int k = lane; k < LK; k += 64) sc[r][k] *= inv;
    }
    float acc[5];
    #pragma unroll
    for (int i = 0; i < 5; i++) acc[i] = 0.f;
    const float* vbase = Vp + ((size_t)b * LK) * ld + h * 64;
    for (int T = 0; T < ntile; T++) {
        __syncthreads();
        #pragma unroll
        for (int it = 0; it < 4; it++) {
            int t = tid + it * 256;
            int kk = t >> 4, seg = t & 15;
            float4 v = *(const float4*)(vbase + (size_t)(T * 64 + kk) * ld + seg * 4);
            float* dst = &kv[kk][seg * 4];
            dst[0] = v.x; dst[1] = v.y; dst[2] = v.z; dst[3] = v.w;
        }
        __syncthreads();
        int ri = 0;
        for (int r = wave; r < nr; r += 4, ri++) {
            float a = 0.f;
            #pragma unroll
            for (int kk = 0; kk < 64; kk++) a += sc[r][T * 64 + kk] * kv[kk][lane];
            acc[ri] += a;
        }
    }
    int ri = 0;
    for (int r = wave; r < nr; r += 4, ri++)
        ctxb[((size_t)(b * LQ + ls[r])) * 512 + h * 64 + lane] = f2bf(acc[ri]);
}

// per-row layer norm, D=512; optional bf16 mirror
__global__ __launch_bounds__(256) void ln_k(const float* __restrict__ in,
                                            float* __restrict__ out, short* __restrict__ outb) {
    __shared__ float red[256];
    int r = blockIdx.x;
    int tid = threadIdx.x;
    const float* x = in + (size_t)r * 512;
    float a = x[tid], b = x[tid + 256];
    red[tid] = a + b;
    __syncthreads();
    for (int s = 128; s > 0; s >>= 1) {
        if (tid < s) red[tid] += red[tid + s];
        __syncthreads();
    }
    float mu = red[0] / 512.f;
    __syncthreads();
    float d1 = a - mu, d2 = b - mu;
    red[tid] = d1 * d1 + d2 * d2;
    __syncthreads();
    for (int s = 128; s > 0; s >>= 1) {
        if (tid < s) red[tid] += red[tid + s];
        __syncthreads();
    }
    float inv = 1.0f / sqrtf(red[0] / 512.f + 1e-5f);
    float v1 = d1 * inv, v2 = d2 * inv;
    out[(size_t)r * 512 + tid] = v1;
    out[(size_t)r * 512 + tid + 256] = v2;
    if (outb) {
        outb[(size_t)r * 512 + tid] = f2bf(v1);
        outb[(size_t)r * 512 + tid + 256] = f2bf(v2);
    }
}

// circular-pad im2col -> bf16
__global__ void xcat_k(const float* __restrict__ x, short* __restrict__ xc, int L, int total) {
    int t = blockIdx.x * 256 + threadIdx.x;
    if (t >= total) return;
    int i = t % 512;
    int h = (t / 512) % 3;
    int bt = t / 1536;
    int tt = bt % L;
    int b = bt / L;
    int src = (tt + h - 1 + L) % L;
    xc[t] = f2bf(x[(size_t)(b * L + src) * 512 + i]);
}

// bn stage 1: per-chunk per-channel sum/sumsq, coalesced row reads. grid=128.
__global__ __launch_bounds__(256) void bnpart_k(const float* __restrict__ y,
                                                float* __restrict__ ps, float* __restrict__ pq,
                                                int rows) {
    int chunk = blockIdx.x;
    int rpc = rows >> 7;
    int r0 = chunk * rpc;
    int tid = threadIdx.x;
    float s0 = 0.f, s1 = 0.f, q0 = 0.f, q1 = 0.f;
    for (int r = r0; r < r0 + rpc; r++) {
        float a = y[(size_t)r * 512 + tid];
        float b = y[(size_t)r * 512 + tid + 256];
        s0 += a; q0 += a * a;
        s1 += b; q1 += b * b;
    }
    ps[chunk * 512 + tid] = s0;
    ps[chunk * 512 + tid + 256] = s1;
    pq[chunk * 512 + tid] = q0;
    pq[chunk * 512 + tid + 256] = q1;
}

// bn stage 2: mu = s/n; var = q/n - mu^2.
__global__ void bnfin_k(const float* __restrict__ ps, const float* __restrict__ pq,
                        float* __restrict__ mu, float* __restrict__ var, int rows) {
    int o = blockIdx.x * 256 + threadIdx.x;
    if (o >= 512) return;
    float s = 0.f, q = 0.f;
    for (int c = 0; c < 128; c++) {
        s += ps[c * 512 + o];
        q += pq[c * 512 + o];
    }
    float m = s / (float)rows;
    mu[o] = m;
    var[o] = q / (float)rows - m * m;
}

// normalize -> max-pool(3,2,pad1) -> elu; writes fp32 + bf16 mirror
__global__ void elu_pool_k(const float* __restrict__ y, const float* __restrict__ mu,
                           const float* __restrict__ var, float* __restrict__ out,
                           short* __restrict__ outb, int L, int total) {
    int t = blockIdx.x * 256 + threadIdx.x;
    if (t >= total) return;
    int o = t % 512;
    int tp = (t / 512) % (L / 2);
    int b = t / (512 * (L / 2));
    float mm = mu[o];
    float inv = 1.0f / sqrtf(var[o] + 1e-5f);
    float m = -INFINITY;
    #pragma unroll
    for (int dt = 0; dt < 3; dt++) {
        int tt = 2 * tp - 1 + dt;
        if (tt < 0 || tt >= L) continue;
        float v = (y[(size_t)(b * L + tt) * 512 + o] - mm) * inv;
        m = fmaxf(m, v);
    }
    float r = m > 0.f ? m : expm1f(m);
    out[t] = r;
    outb[t] = f2bf(r);
}

// out[r] = dot(x[r,:512], w) + b
__global__ void final_k(const float* __restrict__ x, const float* __restrict__ w,
                        const float* __restrict__ bb, float* __restrict__ out, int rows) {
    int gid = blockIdx.x * 256 + threadIdx.x;
    int wid = gid >> 6;
    int lane = gid & 63;
    if (wid >= rows) return;
    const float* xr = x + (size_t)wid * 512;
    float acc = 0.f;
    for (int k = lane; k < 512; k += 64) acc += xr[k] * w[k];
    for (int off = 32; off > 0; off >>= 1) acc += __shfl_down(acc, off);
    if (lane == 0) out[wid] = acc + bb[0];
}

// ---------------------------------------------------------------------------
// Host driver
// ---------------------------------------------------------------------------

static inline int iceil_log(int L) { return (int)ceil(log((double)L)); }
static inline int imin(int a, int b) { return a < b ? a : b; }

extern "C" void kernel_launch(void* const* d_in, const int* in_sizes, int n_in,
                              void* d_out, int out_size, void* d_ws, size_t ws_size,
                              hipStream_t stream) {
    const float* IN  = (const float*)d_in[0];
    const float* Wq  = (const float*)d_in[1];
    const float* bq  = (const float*)d_in[2];
    const float* Wk  = (const float*)d_in[3];
    const float* bk  = (const float*)d_in[4];
    const float* Wv  = (const float*)d_in[5];
    const float* bv  = (const float*)d_in[6];
    const float* Wo  = (const float*)d_in[7];
    const float* bo  = (const float*)d_in[8];
    const float* ew1 = (const float*)d_in[9];
    const float* eb1 = (const float*)d_in[10];
    const float* ew2 = (const float*)d_in[11];
    const float* eb2 = (const float*)d_in[12];
    const float* dw1 = (const float*)d_in[13];
    const float* db1 = (const float*)d_in[14];
    const float* dw2 = (const float*)d_in[15];
    const float* db2 = (const float*)d_in[16];
    const float* DW  = (const float*)d_in[17];
    const float* db  = (const float*)d_in[18];
    const float* ow  = (const float*)d_in[19];
    const float* ob  = (const float*)d_in[20];
    float* OUT = (float*)d_out;

    float* ws = (float*)d_ws;
    size_t off = 0;
    auto alloc = [&](size_t n) { float* p = ws + off; off += n; return p; };
    float* PE   = alloc(4194304);
    short* PEb  = (short*)alloc(2097152);
    float* QKV  = alloc(12582912);
    float* CTX  = alloc(4194304);
    short* CTXb = (short*)alloc(2097152);
    float* T1   = alloc(4194304);
    short* T1b  = (short*)alloc(2097152);
    float* XLN  = alloc(4194304);
    short* XLNb = (short*)alloc(2097152);
    float* T2   = alloc(4194304);
    short* T2b  = (short*)alloc(2097152);
    float* T3   = alloc(4194304);
    short* HIDb = (short*)alloc(8388608);
    float* D1   = alloc(2097152);
    short* D1b  = (short*)alloc(1048576);
    float* D2   = alloc(1048576);
    short* D2b  = (short*)alloc(524288);
    short* Ebb  = (short*)alloc(262144);
    float* Ebf  = alloc(524288);
    float* MB   = alloc(65536);
    float* VM   = alloc(8192);
    float* MU   = alloc(512);
    float* VARb = alloc(512);
    float* BQKV = alloc(1536);
    float* PS   = alloc(65536);
    float* PQ   = alloc(65536);
    int* IDX  = (int*)alloc(17920);
    int* TOPB = (int*)alloc(4480);
    short* WqkvT = (short*)alloc(393216);
    short* WoT   = (short*)alloc(131072);
    short* ew1T  = (short*)alloc(524288);
    short* ew2T  = (short*)alloc(524288);
    short* dw1T  = (short*)alloc(524288);
    short* dw2T  = (short*)alloc(524288);
    short* W2T   = (short*)alloc(393216);
    (void)ws_size; (void)n_in; (void)in_sizes; (void)out_size;

    static_assert(512 * 65 * 4 == 133120, "");
    hipError_t attr_ok = hipFuncSetAttribute(
        (const void*)msamp_lds_k, hipFuncAttributeMaxDynamicSharedMemorySize, 133120);

    auto gemm128 = [&](const short* A, const short* Bt, const float* bias, const float* res,
                       float* C32, short* C16, int M, int N, int K, int relu, int ldC) {
        gemm128_k<<<(N / 128) * (M / 128), 256, 0, stream>>>(A, Bt, bias, res, C32, C16,
                                                             M, N, K, relu, ldC);
    };
    auto gemm64 = [&](const short* A, const short* Bt, const float* bias, const float* res,
                      float* C32, short* C16, int M, int N, int K, int relu, int ldC) {
        gemm64_k<<<(N / 64) * (M / 64), 256, 0, stream>>>(A, Bt, bias, res, C32, C16,
                                                          M, N, K, relu, ldC);
    };
    auto tr = [&](const float* W, short* Wt, int K, int N) {
        dim3 g(N / 32, K / 32);
        transpose_bf16_k<<<g, 256, 0, stream>>>(W, Wt, K, N);
    };

    auto attn = [&](const short* qinb, const short* kvinb, const float* resp,
                    float* out32, short* out16, int LQ, int LK, int ikey) {
        int Mq = 16 * LQ, Mk = 16 * LK;
        const int ld = 1536;
        float* Qp = QKV;
        float* Kp = QKV + 512;
        float* Vp = QKV + 1024;
        if (qinb == kvinb) {
            gemm128(qinb, WqkvT, BQKV, nullptr, QKV, nullptr, Mq, 1536, 512, 0, ld);
        } else {
            gemm64(qinb, WqkvT, BQKV, nullptr, QKV, nullptr, Mq, 512, 512, 0, ld);
            gemm64(kvinb, WqkvT + 512 * 512, BQKV + 512, nullptr, QKV + 512, nullptr,
                   Mk, 1024, 512, 0, ld);
        }
        int U = imin(5 * iceil_log(LK), LK);
        int u = imin(5 * iceil_log(LQ), LQ);
        unsigned rk0, rk1;
        threefry2x32(0u, 42u, 0u, (unsigned)ikey, rk0, rk1);
        int size = LQ * U;
        ridx_k<<<(size + 255) / 256, 256, 0, stream>>>(rk0, rk1, size, (unsigned)(LK - 1), IDX);
        size_t shbytes = (size_t)LK * 65 * 4;
        if (attr_ok == hipSuccess || shbytes <= 65536) {
            msamp_lds_k<<<16 * 8 * 2, 256, shbytes, stream>>>(Qp, Kp, IDX, MB, LQ, LK, U, ld);
        } else {
            int totM = 16 * 8 * LQ * 4;
            msamp_k<<<(totM + 255) / 256, 256, 0, stream>>>(Qp, Kp, IDX, MB, LQ, LK, U, ld);
        }
        topk_k<<<128, 256, 0, stream>>>(MB, TOPB, LQ, u);
        vmean_k<<<dim3(16, 16), 256, 0, stream>>>(Vp, VM, LK, ld);
        int totC = 16 * LQ * 512;
        ctx_fill_k<<<(totC + 255) / 256, 256, 0, stream>>>(VM, CTXb, LQ, totC);
        attn_flash_k<<<16 * 8 * 2, 256, 0, stream>>>(Qp, Kp, Vp, TOPB, CTXb, LQ, LK, u, ld);
        gemm64(CTXb, WoT, bo, resp, out32, out16, Mq, 512, 512, 0, 512);
    };

    auto encoder = [&](const short* Xb, const float* X, int L, int ikey, float* OUTenc) {
        int M = 16 * L;
        attn(Xb, Xb, X, T1, nullptr, L, L, ikey);
        ln_k<<<M, 256, 0, stream>>>(T1, XLN, XLNb);
        gemm128(XLNb, ew1T, eb1, nullptr, nullptr, HIDb, M, 2048, 512, 1, 2048);
        gemm64(HIDb, ew2T, eb2, XLN, T2, nullptr, M, 512, 2048, 0, 512);
        ln_k<<<M, 256, 0, stream>>>(T2, OUTenc, nullptr);
    };

    auto distill = [&](const float* X, int L, float* OUTd, short* OUTdb) {
        int M = 16 * L;
        int tot = M * 1536;
        xcat_k<<<(tot + 255) / 256, 256, 0, stream>>>(X, HIDb, L, tot);
        gemm64(HIDb, W2T, db, nullptr, CTX, nullptr, M, 512, 1536, 0, 512);
        bnpart_k<<<128, 256, 0, stream>>>(CTX, PS, PQ, M);
        bnfin_k<<<2, 256, 0, stream>>>(PS, PQ, MU, VARb, M);
        int toto = 16 * (L / 2) * 512;
        elu_pool_k<<<(toto + 255) / 256, 256, 0, stream>>>(CTX, MU, VARb, OUTd, OUTdb, L, toto);
    };

    // --- weight conversion (once per launch) ---
    tr(Wq, WqkvT, 512, 512);
    tr(Wk, WqkvT + 512 * 512, 512, 512);
    tr(Wv, WqkvT + 1024 * 512, 512, 512);
    tr(Wo, WoT, 512, 512);
    tr(ew1, ew1T, 512, 2048);
    tr(ew2, ew2T, 2048, 512);
    tr(dw1, dw1T, 512, 2048);
    tr(dw2, dw2T, 2048, 512);
    w2t_k<<<(786432 + 255) / 256, 256, 0, stream>>>(DW, W2T, 786432);
    bcat_k<<<6, 256, 0, stream>>>(bq, bk, bv, BQKV);

    // --- forward ---
    int totPE = 16 * 512 * 512;
    pe_add_k<<<(totPE + 255) / 256, 256, 0, stream>>>(IN, PE, PEb, totPE);

    encoder(PEb, PE, 512, 0, T3); distill(T3, 512, D1, D1b);
    encoder(D1b, D1, 256, 1, T3); distill(T3, 256, D2, D2b);
    encoder(D2b, D2, 128, 2, T3); distill(T3, 128, Ebf, Ebb);

    attn(PEb, PEb, PE, T1, T1b, 512, 512, 3);   // out1 = dec_inp + attn
    attn(T1b, Ebb, T1, T2, T2b, 512, 64, 4);    // out2 = out1 + cross-attn
    gemm128(T2b, dw1T, db1, nullptr, nullptr, HIDb, 8192, 2048, 512, 1, 2048);
    gemm64(HIDb, dw2T, db2, T2, T3, nullptr, 8192, 512, 2048, 0, 512);
    final_k<<<(8192 * 64) / 256, 256, 0, stream>>>(T3, ow, ob, OUT, 8192);
}

// Round 15
// 1608.807 us; speedup vs baseline: 1.0774x; 1.0684x over previous
//
#include <hip/hip_runtime.h>
#include <cstdint>
#include <cmath>

// ---------------------------------------------------------------------------
// Informer forward. Round 15: exact revert to R12 (best measured: 1613us).
// R13 (128-tile at N=512) and R14 (gemm64 BK=64) both regressed — GEMM
// micro-structure is in a local basin; R12's config wins empirically.
// jax.random via threefry2x32 (H2, verified R1).
// ---------------------------------------------------------------------------

#define HD __host__ __device__

typedef short short8 __attribute__((ext_vector_type(8)));
typedef float float4v __attribute__((ext_vector_type(4)));

__device__ inline short f2bf(float f) {  // RNE
    unsigned u = __float_as_uint(f);
    unsigned r = u + 0x7FFFu + ((u >> 16) & 1u);
    return (short)(r >> 16);
}

HD inline unsigned rotl32(unsigned x, int r) { return (x << r) | (x >> (32 - r)); }
HD inline void tfround(unsigned& x0, unsigned& x1, int r) {
    x0 += x1; x1 = rotl32(x1, r); x1 ^= x0;
}
HD inline void threefry2x32(unsigned k0, unsigned k1, unsigned c0, unsigned c1,
                            unsigned& o0, unsigned& o1) {
    unsigned ks2 = k0 ^ k1 ^ 0x1BD11BDAu;
    unsigned x0 = c0 + k0, x1 = c1 + k1;
    tfround(x0, x1, 13); tfround(x0, x1, 15); tfround(x0, x1, 26); tfround(x0, x1, 6);
    x0 += k1; x1 += ks2 + 1u;
    tfround(x0, x1, 17); tfround(x0, x1, 29); tfround(x0, x1, 16); tfround(x0, x1, 24);
    x0 += ks2; x1 += k0 + 2u;
    tfround(x0, x1, 13); tfround(x0, x1, 15); tfround(x0, x1, 26); tfround(x0, x1, 6);
    x0 += k0; x1 += k1 + 3u;
    tfround(x0, x1, 17); tfround(x0, x1, 29); tfround(x0, x1, 16); tfround(x0, x1, 24);
    x0 += k1; x1 += ks2 + 4u;
    tfround(x0, x1, 13); tfround(x0, x1, 15); tfround(x0, x1, 26); tfround(x0, x1, 6);
    x0 += ks2; x1 += k0 + 5u;
    o0 = x0; o1 = x1;
}

// ---------------------------------------------------------------------------
// Kernels
// ---------------------------------------------------------------------------

// out = in + PE; outb = bf16(out)
__global__ void pe_add_k(const float* __restrict__ in, float* __restrict__ out,
                         short* __restrict__ outb, int total) {
    int t = blockIdx.x * 256 + threadIdx.x;
    if (t >= total) return;
    int d = t % 512;
    int l = (t / 512) % 512;
    float i2 = (float)(d & ~1);
    float div = expf(i2 * (-0.017988946039016f));  // -ln(10000)/512
    float ang = (float)l * div;
    float v = (d & 1) ? cosf(ang) : sinf(ang);
    float r = in[t] + v;
    out[t] = r;
    outb[t] = f2bf(r);
}

// fp32 [K][N] -> bf16 [N][K] via 32x32 LDS tile
__global__ __launch_bounds__(256) void transpose_bf16_k(const float* __restrict__ in,
                                                        short* __restrict__ out, int K, int N) {
    __shared__ float tile[32][33];
    int k0 = blockIdx.y * 32, n0 = blockIdx.x * 32;
    int c = threadIdx.x & 31, r0 = threadIdx.x >> 5;
    for (int rr = r0; rr < 32; rr += 8)
        tile[rr][c] = in[(size_t)(k0 + rr) * N + n0 + c];
    __syncthreads();
    for (int rr = r0; rr < 32; rr += 8)
        out[(size_t)(n0 + rr) * K + k0 + c] = f2bf(tile[c][rr]);
}

// dist_w (O,I,H) -> bf16 W2T[o][h*512+i]
__global__ void w2t_k(const float* __restrict__ dw, short* __restrict__ out, int total) {
    int t = blockIdx.x * 256 + threadIdx.x;
    if (t >= total) return;
    int kk = t % 1536;
    int o = t / 1536;
    int h = kk / 512, i = kk % 512;
    out[t] = f2bf(dw[(size_t)o * 1536 + i * 3 + h]);
}

// concat biases bq|bk|bv -> bqkv[1536]
__global__ void bcat_k(const float* __restrict__ b0, const float* __restrict__ b1,
                       const float* __restrict__ b2, float* __restrict__ out) {
    int t = blockIdx.x * 256 + threadIdx.x;
    if (t >= 1536) return;
    out[t] = (t < 512) ? b0[t] : (t < 1024 ? b1[t - 512] : b2[t - 1024]);
}

__device__ inline void swizzle_bid(int bid, int nbx, int nby, int& bm, int& bn) {
    if ((nby & 7) == 0) {
        int stripe = nby >> 3;
        int x = bid & 7, w = bid >> 3;
        bn = w % nbx;
        bm = x * stripe + w / nbx;
    } else {
        bn = bid % nbx;
        bm = bid / nbx;
    }
}

// bf16 MFMA GEMM, 128x128 tile, BK=32; A bf16 [M][K], Bt bf16 [N][K].
__global__ __launch_bounds__(256) void gemm128_k(
    const short* __restrict__ A, const short* __restrict__ Bt,
    const float* __restrict__ bias, const float* __restrict__ res,
    float* __restrict__ C32, short* __restrict__ C16,
    int M, int N, int K, int relu, int ldC) {
    __shared__ short As[128 * 40];
    __shared__ short Bs[128 * 40];
    int tid = threadIdx.x;
    int wave = tid >> 6, lane = tid & 63;
    int wy = wave >> 1, wx = wave & 1;
    int rl = lane & 15, quad = lane >> 4;
    int bm, bn;
    swizzle_bid(blockIdx.x, N >> 7, M >> 7, bm, bn);
    bm <<= 7; bn <<= 7;

    float4v acc[4][4];
    #pragma unroll
    for (int i = 0; i < 4; i++)
        #pragma unroll
        for (int j = 0; j < 4; j++) acc[i][j] = (float4v){0.f, 0.f, 0.f, 0.f};

    for (int k0 = 0; k0 < K; k0 += 32) {
        #pragma unroll
        for (int it = 0; it < 2; it++) {
            int c = tid + it * 256;
            int row = c >> 2, seg = c & 3;
            *(float4*)&As[row * 40 + seg * 8] =
                *(const float4*)(A + (size_t)(bm + row) * K + k0 + seg * 8);
        }
        #pragma unroll
        for (int it = 0; it < 2; it++) {
            int c = tid + it * 256;
            int row = c >> 2, seg = c & 3;
            *(float4*)&Bs[row * 40 + seg * 8] =
                *(const float4*)(Bt + (size_t)(bn + row) * K + k0 + seg * 8);
        }
        __syncthreads();
        short8 a[4], b[4];
        #pragma unroll
        for (int i = 0; i < 4; i++)
            a[i] = *(const short8*)&As[(wy * 64 + i * 16 + rl) * 40 + quad * 8];
        #pragma unroll
        for (int j = 0; j < 4; j++)
            b[j] = *(const short8*)&Bs[(wx * 64 + j * 16 + rl) * 40 + quad * 8];
        #pragma unroll
        for (int i = 0; i < 4; i++)
            #pragma unroll
            for (int j = 0; j < 4; j++)
                acc[i][j] = __builtin_amdgcn_mfma_f32_16x16x32_bf16(a[i], b[j], acc[i][j], 0, 0, 0);
        __syncthreads();
    }
    #pragma unroll
    for (int i = 0; i < 4; i++) {
        #pragma unroll
        for (int r = 0; r < 4; r++) {
            int gm = bm + wy * 64 + i * 16 + quad * 4 + r;
            #pragma unroll
            for (int j = 0; j < 4; j++) {
                int gn = bn + wx * 64 + j * 16 + rl;
                float v = acc[i][j][r];
                if (bias) v += bias[gn];
                if (relu) v = fmaxf(v, 0.f);
                if (res) v += res[(size_t)gm * ldC + gn];
                if (C32) C32[(size_t)gm * ldC + gn] = v;
                if (C16) C16[(size_t)gm * ldC + gn] = f2bf(v);
            }
        }
    }
}

// 64x64-tile variant, BK=32. 4 waves, each 16x64.
__global__ __launch_bounds__(256) void gemm64_k(
    const short* __restrict__ A, const short* __restrict__ Bt,
    const float* __restrict__ bias, const float* __restrict__ res,
    float* __restrict__ C32, short* __restrict__ C16,
    int M, int N, int K, int relu, int ldC) {
    __shared__ short As[64 * 40];
    __shared__ short Bs[64 * 40];
    int tid = threadIdx.x;
    int wave = tid >> 6, lane = tid & 63;
    int rl = lane & 15, quad = lane >> 4;
    int bm, bn;
    swizzle_bid(blockIdx.x, N >> 6, M >> 6, bm, bn);
    bm <<= 6; bn <<= 6;

    float4v acc[4];
    #pragma unroll
    for (int j = 0; j < 4; j++) acc[j] = (float4v){0.f, 0.f, 0.f, 0.f};

    int row = tid >> 2, seg = tid & 3;
    for (int k0 = 0; k0 < K; k0 += 32) {
        *(float4*)&As[row * 40 + seg * 8] =
            *(const float4*)(A + (size_t)(bm + row) * K + k0 + seg * 8);
        *(float4*)&Bs[row * 40 + seg * 8] =
            *(const float4*)(Bt + (size_t)(bn + row) * K + k0 + seg * 8);
        __syncthreads();
        short8 a = *(const short8*)&As[(wave * 16 + rl) * 40 + quad * 8];
        short8 b[4];
        #pragma unroll
        for (int j = 0; j < 4; j++)
            b[j] = *(const short8*)&Bs[(j * 16 + rl) * 40 + quad * 8];
        #pragma unroll
        for (int j = 0; j < 4; j++)
            acc[j] = __builtin_amdgcn_mfma_f32_16x16x32_bf16(a, b[j], acc[j], 0, 0, 0);
        __syncthreads();
    }
    #pragma unroll
    for (int r = 0; r < 4; r++) {
        int gm = bm + wave * 16 + quad * 4 + r;
        #pragma unroll
        for (int j = 0; j < 4; j++) {
            int gn = bn + j * 16 + rl;
            float v = acc[j][r];
            if (bias) v += bias[gn];
            if (relu) v = fmaxf(v, 0.f);
            if (res) v += res[(size_t)gm * ldC + gn];
            if (C32) C32[(size_t)gm * ldC + gn] = v;
            if (C16) C16[(size_t)gm * ldC + gn] = f2bf(v);
        }
    }
}

// idx[j] = threefry(rkey, (j, j+size)).second & mask   (H2, verified R1)
__global__ void ridx_k(unsigned k0, unsigned k1, int size, unsigned mask, int* __restrict__ idx) {
    int j = blockIdx.x * 256 + threadIdx.x;
    if (j >= size) return;
    unsigned o0, o1;
    threefry2x32(k0, k1, (unsigned)j, (unsigned)(j + size), o0, o1);
    idx[j] = (int)(o1 & mask);
}

// msamp, K-slab in LDS. One block per (b, h, l-half); grid 16*8*2 = 256.
extern __shared__ float kslab[];
__global__ __launch_bounds__(256) void msamp_lds_k(
    const float* __restrict__ Qp, const float* __restrict__ Kp,
    const int* __restrict__ idx, float* __restrict__ Mout,
    int LQ, int LK, int U, int ld) {
    int bid = blockIdx.x;
    int half = bid & 1;
    int bh = bid >> 1;
    int h = bh & 7, b = bh >> 3;
    const float* kbase = Kp + (size_t)b * LK * ld + h * 64;
    for (int t = threadIdx.x; t < LK * 16; t += 256) {
        int r = t >> 4, seg = t & 15;
        float4 v = *(const float4*)(kbase + (size_t)r * ld + seg * 4);
        float* dst = &kslab[r * 65 + seg * 4];
        dst[0] = v.x; dst[1] = v.y; dst[2] = v.z; dst[3] = v.w;
    }
    __syncthreads();
    int halfL = LQ >> 1;
    for (int li = threadIdx.x; li < halfL; li += 256) {
        int l = half * halfL + li;
        const float4* q = (const float4*)(Qp + (size_t)(b * LQ + l) * ld + h * 64);
        float qr[64];
        #pragma unroll
        for (int d4 = 0; d4 < 16; d4++) {
            float4 v = q[d4];
            qr[4 * d4] = v.x; qr[4 * d4 + 1] = v.y; qr[4 * d4 + 2] = v.z; qr[4 * d4 + 3] = v.w;
        }
        const int* ip = idx + l * U;
        float mx = -INFINITY, sm = 0.f;
        for (int s = 0; s < U; s++) {
            const float* kr = &kslab[ip[s] * 65];
            float acc = 0.f;
            #pragma unroll
            for (int d = 0; d < 64; d++) acc += qr[d] * kr[d];
            mx = fmaxf(mx, acc);
            sm += acc;
        }
        Mout[(size_t)bh * LQ + l] = mx - sm / (float)LK;
    }
}

// Fallback msamp if large dynamic-LDS attribute fails.
__global__ void msamp_k(const float* __restrict__ Qp, const float* __restrict__ Kp,
                        const int* __restrict__ idx, float* __restrict__ Mout,
                        int LQ, int LK, int U, int ld) {
    int t = blockIdx.x * 256 + threadIdx.x;
    int total = 16 * 8 * LQ * 4;
    if (t >= total) return;
    int p = t & 3;
    int rest = t >> 2;
    int l = rest % LQ;
    int h = (rest / LQ) & 7;
    int b = rest / (LQ * 8);
    const float4* q = (const float4*)(Qp + ((size_t)(b * LQ + l) * ld + h * 64));
    const float* kb = Kp + ((size_t)b * LK * ld + h * 64);
    float4 qr[16];
    #pragma unroll
    for (int d = 0; d < 16; d++) qr[d] = q[d];
    float mx = -INFINITY, sm = 0.f;
    for (int s = p; s < U; s += 4) {
        const float4* kr = (const float4*)(kb + (size_t)idx[l * U + s] * ld);
        float acc = 0.f;
        #pragma unroll
        for (int d = 0; d < 16; d++) {
            float4 kv = kr[d];
            acc += qr[d].x * kv.x + qr[d].y * kv.y + qr[d].z * kv.z + qr[d].w * kv.w;
        }
        mx = fmaxf(mx, acc);
        sm += acc;
    }
    mx = fmaxf(mx, __shfl_xor(mx, 1));
    mx = fmaxf(mx, __shfl_xor(mx, 2));
    sm += __shfl_xor(sm, 1);
    sm += __shfl_xor(sm, 2);
    if (p == 0)
        Mout[(size_t)((b * 8) + h) * LQ + l] = mx - sm / (float)LK;
}

// Parallel top-u per (b,h): iterative argmax in LDS, lowest-index tie-break.
__global__ __launch_bounds__(256) void topk_k(const float* __restrict__ M,
                                              int* __restrict__ top, int LQ, int u) {
    __shared__ float vals[512];
    __shared__ float rv[256];
    __shared__ int ri[256];
    int bh = blockIdx.x;
    int tid = threadIdx.x;
    const float* m = M + (size_t)bh * LQ;
    for (int l = tid; l < LQ; l += 256) vals[l] = m[l];
    __syncthreads();
    for (int j = 0; j < u; j++) {
        float best = -INFINITY;
        int bi = LQ;
        for (int l = tid; l < LQ; l += 256) {
            float v = vals[l];
            if (v > best) { best = v; bi = l; }
        }
        rv[tid] = best; ri[tid] = bi;
        __syncthreads();
        for (int s = 128; s > 0; s >>= 1) {
            if (tid < s) {
                float v2 = rv[tid + s]; int i2 = ri[tid + s];
                if (v2 > rv[tid] || (v2 == rv[tid] && i2 < ri[tid])) { rv[tid] = v2; ri[tid] = i2; }
            }
            __syncthreads();
        }
        int sel = ri[0];
        if (tid == 0) {
            top[bh * u + j] = sel;
            vals[sel] = -INFINITY;
        }
        __syncthreads();
    }
}

// vm[b,c] = mean over l of V[b,l,c]; parallel over l. grid (16 c-chunks, 16 b).
__global__ __launch_bounds__(256) void vmean_k(const float* __restrict__ Vp,
                                               float* __restrict__ vm, int LK, int ld) {
    __shared__ float red[8][33];
    int b = blockIdx.y;
    int c0 = blockIdx.x * 32;
    int ci = threadIdx.x & 31, g = threadIdx.x >> 5;
    const float* base = Vp + (size_t)b * LK * ld + c0 + ci;
    float s = 0.f;
    for (int l = g; l < LK; l += 8) s += base[(size_t)l * ld];
    red[g][ci] = s;
    __syncthreads();
    if (threadIdx.x < 32) {
        float t = 0.f;
        #pragma unroll
        for (int g2 = 0; g2 < 8; g2++) t += red[g2][threadIdx.x];
        vm[b * 512 + c0 + threadIdx.x] = t / (float)LK;
    }
}

// ctxb[b,l,c] = bf16(vm[b,c])
__global__ void ctx_fill_k(const float* __restrict__ vm, short* __restrict__ ctxb,
                           int LQ, int total) {
    int t = blockIdx.x * 256 + threadIdx.x;
    if (t >= total) return;
    int c = t % 512;
    int b = t / (512 * LQ);
    ctxb[t] = f2bf(vm[b * 512 + c]);
}

// Flash-style ProbSparse attention: one block per (b, h, u-half), 256 threads.
__global__ __launch_bounds__(256) void attn_flash_k(
    const float* __restrict__ Qp, const float* __restrict__ Kp, const float* __restrict__ Vp,
    const int* __restrict__ top, short* __restrict__ ctxb, int LQ, int LK, int u, int ld) {
    __shared__ float qs[18][64];
    __shared__ int ls[18];
    __shared__ float kv[64][65];
    __shared__ float sc[18][512];
    int bid = blockIdx.x;
    int chunk = bid & 1;  // 2 chunks per (b,h)
    int h = (bid >> 1) & 7;
    int b = bid >> 4;
    int CH = (u + 1) >> 1;
    int r0 = chunk * CH;
    int nr = min(CH, u - r0);
    int tid = threadIdx.x;
    int wave = tid >> 6, lane = tid & 63;

    if (tid < nr) ls[tid] = top[((b * 8) + h) * u + r0 + tid];
    __syncthreads();
    for (int t = tid; t < nr * 16; t += 256) {
        int r = t >> 4, seg = t & 15;
        float4 v = *(const float4*)(Qp + ((size_t)(b * LQ + ls[r])) * ld + h * 64 + seg * 4);
        float* dst = &qs[r][seg * 4];
        dst[0] = v.x; dst[1] = v.y; dst[2] = v.z; dst[3] = v.w;
    }

    int ntile = LK >> 6;
    const float* kbase = Kp + ((size_t)b * LK) * ld + h * 64;
    for (int T = 0; T < ntile; T++) {
        __syncthreads();
        #pragma unroll
        for (int it = 0; it < 4; it++) {
            int t = tid + it * 256;
            int kk = t >> 4, seg = t & 15;
            float4 v = *(const float4*)(kbase + (size_t)(T * 64 + kk) * ld + seg * 4);
            float* dst = &kv[kk][seg * 4];
            dst[0] = v.x; dst[1] = v.y; dst[2] = v.z; dst[3] = v.w;
        }
        __syncthreads();
        for (int p = tid; p < nr * 64; p += 256) {
            int r = p >> 6, kk = p & 63;
            float acc = 0.f;
            #pragma unroll
            for (int d = 0; d < 64; d++) acc += qs[r][d] * kv[kk][d];
            sc[r][T * 64 + kk] = acc * 0.125f;  // 1/sqrt(64)
        }
    }
    __syncthreads();
    for (int r = wave; r < nr; r += 4) {
        float mx = -INFINITY;
        for (int k = lane; k < LK; k += 64) mx = fmaxf(mx, sc[r][k]);
        #pragma unroll
        for (int o = 32; o > 0; o >>= 1) mx = fmaxf(mx, __shfl_xor(mx, o));
        float s = 0.f;
        for (int k = lane; k < LK; k += 64) {
            float e = expf(sc[r][k] - mx);
            sc[r][k] = e;
            s += e;
        }
        #pragma unroll
        for (int o = 32; o > 0; o >>= 1) s += __shfl_xor(s, o);
        float inv = 1.0f / s;
        for (int k = lane; k < LK; k += 64) sc[r][k] *= inv;
    }
    float acc[5];
    #pragma unroll
    for (int i = 0; i < 5; i++) acc[i] = 0.f;
    const float* vbase = Vp + ((size_t)b * LK) * ld + h * 64;
    for (int T = 0; T < ntile; T++) {
        __syncthreads();
        #pragma unroll
        for (int it = 0; it < 4; it++) {
            int t = tid + it * 256;
            int kk = t >> 4, seg = t & 15;
            float4 v = *(const float4*)(vbase + (size_t)(T * 64 + kk) * ld + seg * 4);
            float* dst = &kv[kk][seg * 4];
            dst[0] = v.x; dst[1] = v.y; dst[2] = v.z; dst[3] = v.w;
        }
        __syncthreads();
        int ri = 0;
        for (int r = wave; r < nr; r += 4, ri++) {
            float a = 0.f;
            #pragma unroll
            for (int kk = 0; kk < 64; kk++) a += sc[r][T * 64 + kk] * kv[kk][lane];
            acc[ri] += a;
        }
    }
    int ri = 0;
    for (int r = wave; r < nr; r += 4, ri++)
        ctxb[((size_t)(b * LQ + ls[r])) * 512 + h * 64 + lane] = f2bf(acc[ri]);
}

// per-row layer norm, D=512; optional bf16 mirror
__global__ __launch_bounds__(256) void ln_k(const float* __restrict__ in,
                                            float* __restrict__ out, short* __restrict__ outb) {
    __shared__ float red[256];
    int r = blockIdx.x;
    int tid = threadIdx.x;
    const float* x = in + (size_t)r * 512;
    float a = x[tid], b = x[tid + 256];
    red[tid] = a + b;
    __syncthreads();
    for (int s = 128; s > 0; s >>= 1) {
        if (tid < s) red[tid] += red[tid + s];
        __syncthreads();
    }
    float mu = red[0] / 512.f;
    __syncthreads();
    float d1 = a - mu, d2 = b - mu;
    red[tid] = d1 * d1 + d2 * d2;
    __syncthreads();
    for (int s = 128; s > 0; s >>= 1) {
        if (tid < s) red[tid] += red[tid + s];
        __syncthreads();
    }
    float inv = 1.0f / sqrtf(red[0] / 512.f + 1e-5f);
    float v1 = d1 * inv, v2 = d2 * inv;
    out[(size_t)r * 512 + tid] = v1;
    out[(size_t)r * 512 + tid + 256] = v2;
    if (outb) {
        outb[(size_t)r * 512 + tid] = f2bf(v1);
        outb[(size_t)r * 512 + tid + 256] = f2bf(v2);
    }
}

// circular-pad im2col -> bf16
__global__ void xcat_k(const float* __restrict__ x, short* __restrict__ xc, int L, int total) {
    int t = blockIdx.x * 256 + threadIdx.x;
    if (t >= total) return;
    int i = t % 512;
    int h = (t / 512) % 3;
    int bt = t / 1536;
    int tt = bt % L;
    int b = bt / L;
    int src = (tt + h - 1 + L) % L;
    xc[t] = f2bf(x[(size_t)(b * L + src) * 512 + i]);
}

// bn stage 1: per-chunk per-channel sum/sumsq, coalesced row reads. grid=128.
__global__ __launch_bounds__(256) void bnpart_k(const float* __restrict__ y,
                                                float* __restrict__ ps, float* __restrict__ pq,
                                                int rows) {
    int chunk = blockIdx.x;
    int rpc = rows >> 7;
    int r0 = chunk * rpc;
    int tid = threadIdx.x;
    float s0 = 0.f, s1 = 0.f, q0 = 0.f, q1 = 0.f;
    for (int r = r0; r < r0 + rpc; r++) {
        float a = y[(size_t)r * 512 + tid];
        float b = y[(size_t)r * 512 + tid + 256];
        s0 += a; q0 += a * a;
        s1 += b; q1 += b * b;
    }
    ps[chunk * 512 + tid] = s0;
    ps[chunk * 512 + tid + 256] = s1;
    pq[chunk * 512 + tid] = q0;
    pq[chunk * 512 + tid + 256] = q1;
}

// bn stage 2: mu = s/n; var = q/n - mu^2.
__global__ void bnfin_k(const float* __restrict__ ps, const float* __restrict__ pq,
                        float* __restrict__ mu, float* __restrict__ var, int rows) {
    int o = blockIdx.x * 256 + threadIdx.x;
    if (o >= 512) return;
    float s = 0.f, q = 0.f;
    for (int c = 0; c < 128; c++) {
        s += ps[c * 512 + o];
        q += pq[c * 512 + o];
    }
    float m = s / (float)rows;
    mu[o] = m;
    var[o] = q / (float)rows - m * m;
}

// normalize -> max-pool(3,2,pad1) -> elu; writes fp32 + bf16 mirror
__global__ void elu_pool_k(const float* __restrict__ y, const float* __restrict__ mu,
                           const float* __restrict__ var, float* __restrict__ out,
                           short* __restrict__ outb, int L, int total) {
    int t = blockIdx.x * 256 + threadIdx.x;
    if (t >= total) return;
    int o = t % 512;
    int tp = (t / 512) % (L / 2);
    int b = t / (512 * (L / 2));
    float mm = mu[o];
    float inv = 1.0f / sqrtf(var[o] + 1e-5f);
    float m = -INFINITY;
    #pragma unroll
    for (int dt = 0; dt < 3; dt++) {
        int tt = 2 * tp - 1 + dt;
        if (tt < 0 || tt >= L) continue;
        float v = (y[(size_t)(b * L + tt) * 512 + o] - mm) * inv;
        m = fmaxf(m, v);
    }
    float r = m > 0.f ? m : expm1f(m);
    out[t] = r;
    outb[t] = f2bf(r);
}

// out[r] = dot(x[r,:512], w) + b
__global__ void final_k(const float* __restrict__ x, const float* __restrict__ w,
                        const float* __restrict__ bb, float* __restrict__ out, int rows) {
    int gid = blockIdx.x * 256 + threadIdx.x;
    int wid = gid >> 6;
    int lane = gid & 63;
    if (wid >= rows) return;
    const float* xr = x + (size_t)wid * 512;
    float acc = 0.f;
    for (int k = lane; k < 512; k += 64) acc += xr[k] * w[k];
    for (int off = 32; off > 0; off >>= 1) acc += __shfl_down(acc, off);
    if (lane == 0) out[wid] = acc + bb[0];
}

// ---------------------------------------------------------------------------
// Host driver
// ---------------------------------------------------------------------------

static inline int iceil_log(int L) { return (int)ceil(log((double)L)); }
static inline int imin(int a, int b) { return a < b ? a : b; }

extern "C" void kernel_launch(void* const* d_in, const int* in_sizes, int n_in,
                              void* d_out, int out_size, void* d_ws, size_t ws_size,
                              hipStream_t stream) {
    const float* IN  = (const float*)d_in[0];
    const float* Wq  = (const float*)d_in[1];
    const float* bq  = (const float*)d_in[2];
    const float* Wk  = (const float*)d_in[3];
    const float* bk  = (const float*)d_in[4];
    const float* Wv  = (const float*)d_in[5];
    const float* bv  = (const float*)d_in[6];
    const float* Wo  = (const float*)d_in[7];
    const float* bo  = (const float*)d_in[8];
    const float* ew1 = (const float*)d_in[9];
    const float* eb1 = (const float*)d_in[10];
    const float* ew2 = (const float*)d_in[11];
    const float* eb2 = (const float*)d_in[12];
    const float* dw1 = (const float*)d_in[13];
    const float* db1 = (const float*)d_in[14];
    const float* dw2 = (const float*)d_in[15];
    const float* db2 = (const float*)d_in[16];
    const float* DW  = (const float*)d_in[17];
    const float* db  = (const float*)d_in[18];
    const float* ow  = (const float*)d_in[19];
    const float* ob  = (const float*)d_in[20];
    float* OUT = (float*)d_out;

    float* ws = (float*)d_ws;
    size_t off = 0;
    auto alloc = [&](size_t n) { float* p = ws + off; off += n; return p; };
    float* PE   = alloc(4194304);
    short* PEb  = (short*)alloc(2097152);
    float* QKV  = alloc(12582912);
    float* CTX  = alloc(4194304);
    short* CTXb = (short*)alloc(2097152);
    float* T1   = alloc(4194304);
    short* T1b  = (short*)alloc(2097152);
    float* XLN  = alloc(4194304);
    short* XLNb = (short*)alloc(2097152);
    float* T2   = alloc(4194304);
    short* T2b  = (short*)alloc(2097152);
    float* T3   = alloc(4194304);
    short* HIDb = (short*)alloc(8388608);
    float* D1   = alloc(2097152);
    short* D1b  = (short*)alloc(1048576);
    float* D2   = alloc(1048576);
    short* D2b  = (short*)alloc(524288);
    short* Ebb  = (short*)alloc(262144);
    float* Ebf  = alloc(524288);
    float* MB   = alloc(65536);
    float* VM   = alloc(8192);
    float* MU   = alloc(512);
    float* VARb = alloc(512);
    float* BQKV = alloc(1536);
    float* PS   = alloc(65536);
    float* PQ   = alloc(65536);
    int* IDX  = (int*)alloc(17920);
    int* TOPB = (int*)alloc(4480);
    short* WqkvT = (short*)alloc(393216);
    short* WoT   = (short*)alloc(131072);
    short* ew1T  = (short*)alloc(524288);
    short* ew2T  = (short*)alloc(524288);
    short* dw1T  = (short*)alloc(524288);
    short* dw2T  = (short*)alloc(524288);
    short* W2T   = (short*)alloc(393216);
    (void)ws_size; (void)n_in; (void)in_sizes; (void)out_size;

    static_assert(512 * 65 * 4 == 133120, "");
    hipError_t attr_ok = hipFuncSetAttribute(
        (const void*)msamp_lds_k, hipFuncAttributeMaxDynamicSharedMemorySize, 133120);

    auto gemm128 = [&](const short* A, const short* Bt, const float* bias, const float* res,
                       float* C32, short* C16, int M, int N, int K, int relu, int ldC) {
        gemm128_k<<<(N / 128) * (M / 128), 256, 0, stream>>>(A, Bt, bias, res, C32, C16,
                                                             M, N, K, relu, ldC);
    };
    auto gemm64 = [&](const short* A, const short* Bt, const float* bias, const float* res,
                      float* C32, short* C16, int M, int N, int K, int relu, int ldC) {
        gemm64_k<<<(N / 64) * (M / 64), 256, 0, stream>>>(A, Bt, bias, res, C32, C16,
                                                          M, N, K, relu, ldC);
    };
    auto tr = [&](const float* W, short* Wt, int K, int N) {
        dim3 g(N / 32, K / 32);
        transpose_bf16_k<<<g, 256, 0, stream>>>(W, Wt, K, N);
    };

    auto attn = [&](const short* qinb, const short* kvinb, const float* resp,
                    float* out32, short* out16, int LQ, int LK, int ikey) {
        int Mq = 16 * LQ, Mk = 16 * LK;
        const int ld = 1536;
        float* Qp = QKV;
        float* Kp = QKV + 512;
        float* Vp = QKV + 1024;
        if (qinb == kvinb) {
            gemm128(qinb, WqkvT, BQKV, nullptr, QKV, nullptr, Mq, 1536, 512, 0, ld);
        } else {
            gemm64(qinb, WqkvT, BQKV, nullptr, QKV, nullptr, Mq, 512, 512, 0, ld);
            gemm64(kvinb, WqkvT + 512 * 512, BQKV + 512, nullptr, QKV + 512, nullptr,
                   Mk, 1024, 512, 0, ld);
        }
        int U = imin(5 * iceil_log(LK), LK);
        int u = imin(5 * iceil_log(LQ), LQ);
        unsigned rk0, rk1;
        threefry2x32(0u, 42u, 0u, (unsigned)ikey, rk0, rk1);
        int size = LQ * U;
        ridx_k<<<(size + 255) / 256, 256, 0, stream>>>(rk0, rk1, size, (unsigned)(LK - 1), IDX);
        size_t shbytes = (size_t)LK * 65 * 4;
        if (attr_ok == hipSuccess || shbytes <= 65536) {
            msamp_lds_k<<<16 * 8 * 2, 256, shbytes, stream>>>(Qp, Kp, IDX, MB, LQ, LK, U, ld);
        } else {
            int totM = 16 * 8 * LQ * 4;
            msamp_k<<<(totM + 255) / 256, 256, 0, stream>>>(Qp, Kp, IDX, MB, LQ, LK, U, ld);
        }
        topk_k<<<128, 256, 0, stream>>>(MB, TOPB, LQ, u);
        vmean_k<<<dim3(16, 16), 256, 0, stream>>>(Vp, VM, LK, ld);
        int totC = 16 * LQ * 512;
        ctx_fill_k<<<(totC + 255) / 256, 256, 0, stream>>>(VM, CTXb, LQ, totC);
        attn_flash_k<<<16 * 8 * 2, 256, 0, stream>>>(Qp, Kp, Vp, TOPB, CTXb, LQ, LK, u, ld);
        gemm64(CTXb, WoT, bo, resp, out32, out16, Mq, 512, 512, 0, 512);
    };

    auto encoder = [&](const short* Xb, const float* X, int L, int ikey, float* OUTenc) {
        int M = 16 * L;
        attn(Xb, Xb, X, T1, nullptr, L, L, ikey);
        ln_k<<<M, 256, 0, stream>>>(T1, XLN, XLNb);
        gemm128(XLNb, ew1T, eb1, nullptr, nullptr, HIDb, M, 2048, 512, 1, 2048);
        gemm64(HIDb, ew2T, eb2, XLN, T2, nullptr, M, 512, 2048, 0, 512);
        ln_k<<<M, 256, 0, stream>>>(T2, OUTenc, nullptr);
    };

    auto distill = [&](const float* X, int L, float* OUTd, short* OUTdb) {
        int M = 16 * L;
        int tot = M * 1536;
        xcat_k<<<(tot + 255) / 256, 256, 0, stream>>>(X, HIDb, L, tot);
        gemm64(HIDb, W2T, db, nullptr, CTX, nullptr, M, 512, 1536, 0, 512);
        bnpart_k<<<128, 256, 0, stream>>>(CTX, PS, PQ, M);
        bnfin_k<<<2, 256, 0, stream>>>(PS, PQ, MU, VARb, M);
        int toto = 16 * (L / 2) * 512;
        elu_pool_k<<<(toto + 255) / 256, 256, 0, stream>>>(CTX, MU, VARb, OUTd, OUTdb, L, toto);
    };

    // --- weight conversion (once per launch) ---
    tr(Wq, WqkvT, 512, 512);
    tr(Wk, WqkvT + 512 * 512, 512, 512);
    tr(Wv, WqkvT + 1024 * 512, 512, 512);
    tr(Wo, WoT, 512, 512);
    tr(ew1, ew1T, 512, 2048);
    tr(ew2, ew2T, 2048, 512);
    tr(dw1, dw1T, 512, 2048);
    tr(dw2, dw2T, 2048, 512);
    w2t_k<<<(786432 + 255) / 256, 256, 0, stream>>>(DW, W2T, 786432);
    bcat_k<<<6, 256, 0, stream>>>(bq, bk, bv, BQKV);

    // --- forward ---
    int totPE = 16 * 512 * 512;
    pe_add_k<<<(totPE + 255) / 256, 256, 0, stream>>>(IN, PE, PEb, totPE);

    encoder(PEb, PE, 512, 0, T3); distill(T3, 512, D1, D1b);
    encoder(D1b, D1, 256, 1, T3); distill(T3, 256, D2, D2b);
    encoder(D2b, D2, 128, 2, T3); distill(T3, 128, Ebf, Ebb);

    attn(PEb, PEb, PE, T1, T1b, 512, 512, 3);   // out1 = dec_inp + attn
    attn(T1b, Ebb, T1, T2, T2b, 512, 64, 4);    // out2 = out1 + cross-attn
    gemm128(T2b, dw1T, db1, nullptr, nullptr, HIDb, 8192, 2048, 512, 1, 2048);
    gemm64(HIDb, dw2T, db2, T2, T3, nullptr, 8192, 512, 2048, 0, 512);
    final_k<<<(8192 * 64) / 256, 256, 0, stream>>>(T3, ow, ob, OUT, 8192);
}